// Round 1
// baseline (1572.389 us; speedup 1.0000x reference)
//
#include <hip/hip_runtime.h>
#include <math.h>

#define NT 256

// ---------------------------------------------------------------------------
// deg[d] += 1 for every edge destination (self-loop +1 added later in node1).
// ---------------------------------------------------------------------------
__global__ __launch_bounds__(NT) void k_deg(const int* __restrict__ dst,
                                            int* __restrict__ deg, int E) {
    int t = blockIdx.x * blockDim.x + threadIdx.x;
    int base = t * 4;
    if (base + 3 < E) {
        int4 d = ((const int4*)dst)[t];
        atomicAdd(&deg[d.x], 1);
        atomicAdd(&deg[d.y], 1);
        atomicAdd(&deg[d.z], 1);
        atomicAdd(&deg[d.w], 1);
    } else if (base < E) {
        for (int e = base; e < E; ++e) atomicAdd(&deg[dst[e]], 1);
    }
}

// ---------------------------------------------------------------------------
// dinv[i] = rsqrt(deg[i]+1) (self-loop), u[i] = x[i]*dinv[i]
// ---------------------------------------------------------------------------
__global__ __launch_bounds__(NT) void k_node1(const float* __restrict__ x,
                                              const int* __restrict__ deg,
                                              float* __restrict__ dinv,
                                              float* __restrict__ u, int N) {
    int i = blockIdx.x * blockDim.x + threadIdx.x;
    if (i < N) {
        float dv = rsqrtf((float)(deg[i] + 1));
        dinv[i] = dv;
        u[i] = x[i] * dv;
    }
}

// ---------------------------------------------------------------------------
// agg1[d] += u[s]  (layer-1 scalar message aggregation)
// ---------------------------------------------------------------------------
__global__ __launch_bounds__(NT) void k_edge1(const int* __restrict__ src,
                                              const int* __restrict__ dst,
                                              const float* __restrict__ u,
                                              float* __restrict__ agg1, int E) {
    int t = blockIdx.x * blockDim.x + threadIdx.x;
    int base = t * 4;
    if (base + 3 < E) {
        int4 s = ((const int4*)src)[t];
        int4 d = ((const int4*)dst)[t];
        atomicAdd(&agg1[d.x], u[s.x]);
        atomicAdd(&agg1[d.y], u[s.y]);
        atomicAdd(&agg1[d.z], u[s.z]);
        atomicAdd(&agg1[d.w], u[s.w]);
    } else if (base < E) {
        for (int e = base; e < E; ++e) atomicAdd(&agg1[dst[e]], u[src[e]]);
    }
}

// ---------------------------------------------------------------------------
// s1 = (agg1[i]+u[i])*dinv[i];  h = relu(s1*W1+b1) (16);  q[i] = (h@W2)*dinv[i]
// ---------------------------------------------------------------------------
__global__ __launch_bounds__(NT) void k_node2(const float* __restrict__ agg1,
                                              const float* __restrict__ u,
                                              const float* __restrict__ dinv,
                                              const float* __restrict__ W1,
                                              const float* __restrict__ b1,
                                              const float* __restrict__ W2,
                                              float2* __restrict__ q, int N) {
    int i = blockIdx.x * blockDim.x + threadIdx.x;
    if (i < N) {
        float dv = dinv[i];
        float s1 = (agg1[i] + u[i]) * dv;
        float c0 = 0.f, c1 = 0.f;
#pragma unroll
        for (int k = 0; k < 16; ++k) {
            float h = fmaxf(s1 * W1[k] + b1[k], 0.f);
            c0 += h * W2[2 * k];
            c1 += h * W2[2 * k + 1];
        }
        q[i] = make_float2(c0 * dv, c1 * dv);
    }
}

// ---------------------------------------------------------------------------
// agg2[d] += q[s]  (layer-2 float2 message aggregation)
// ---------------------------------------------------------------------------
__global__ __launch_bounds__(NT) void k_edge2(const int* __restrict__ src,
                                              const int* __restrict__ dst,
                                              const float2* __restrict__ q,
                                              float* __restrict__ agg2, int E) {
    int t = blockIdx.x * blockDim.x + threadIdx.x;
    int base = t * 4;
    if (base + 3 < E) {
        int4 s = ((const int4*)src)[t];
        int4 d = ((const int4*)dst)[t];
        float2 q0 = q[s.x], q1 = q[s.y], q2 = q[s.z], q3 = q[s.w];
        atomicAdd(&agg2[2 * d.x], q0.x);
        atomicAdd(&agg2[2 * d.x + 1], q0.y);
        atomicAdd(&agg2[2 * d.y], q1.x);
        atomicAdd(&agg2[2 * d.y + 1], q1.y);
        atomicAdd(&agg2[2 * d.z], q2.x);
        atomicAdd(&agg2[2 * d.z + 1], q2.y);
        atomicAdd(&agg2[2 * d.w], q3.x);
        atomicAdd(&agg2[2 * d.w + 1], q3.y);
    } else if (base < E) {
        for (int e = base; e < E; ++e) {
            float2 qq = q[src[e]];
            atomicAdd(&agg2[2 * dst[e]], qq.x);
            atomicAdd(&agg2[2 * dst[e] + 1], qq.y);
        }
    }
}

// ---------------------------------------------------------------------------
// o = (agg2[i]+q[i])*dinv[i] + b2;  out = log_softmax(o) over 2 classes
// ---------------------------------------------------------------------------
__global__ __launch_bounds__(NT) void k_node3(const float* __restrict__ agg2,
                                              const float2* __restrict__ q,
                                              const float* __restrict__ dinv,
                                              const float* __restrict__ b2,
                                              float2* __restrict__ out, int N) {
    int i = blockIdx.x * blockDim.x + threadIdx.x;
    if (i < N) {
        float dv = dinv[i];
        float2 qi = q[i];
        float o0 = (agg2[2 * i] + qi.x) * dv + b2[0];
        float o1 = (agg2[2 * i + 1] + qi.y) * dv + b2[1];
        float m = fmaxf(o0, o1);
        float l = m + logf(expf(o0 - m) + expf(o1 - m));
        out[i] = make_float2(o0 - l, o1 - l);
    }
}

extern "C" void kernel_launch(void* const* d_in, const int* in_sizes, int n_in,
                              void* d_out, int out_size, void* d_ws, size_t ws_size,
                              hipStream_t stream) {
    const float* x  = (const float*)d_in[0];
    const int* ei   = (const int*)d_in[1];
    const float* W1 = (const float*)d_in[2];
    const float* b1 = (const float*)d_in[3];
    const float* W2 = (const float*)d_in[4];
    const float* b2 = (const float*)d_in[5];

    const int N = in_sizes[0];          // x is (N,1)
    const int E = in_sizes[1] / 2;      // edge_index is (2,E)
    const int* src = ei;
    const int* dst = ei + E;

    // Workspace layout (bytes). First 16*N bytes must be zeroed (deg|agg1|agg2).
    char* ws = (char*)d_ws;
    int*    deg  = (int*)   (ws);                         // N ints
    float*  agg1 = (float*) (ws + (size_t)4 * N);         // N floats
    float*  agg2 = (float*) (ws + (size_t)8 * N);         // 2N floats
    float*  dinv = (float*) (ws + (size_t)16 * N);        // N floats
    float*  u    = (float*) (ws + (size_t)20 * N);        // N floats
    float2* q    = (float2*)(ws + (size_t)24 * N);        // N float2 (end = 32N)

    hipMemsetAsync(d_ws, 0, (size_t)16 * N, stream);

    const int nodeBlocks = (N + NT - 1) / NT;
    const int edgeBlocks = (E / 4 + NT - 1) / NT + 1;  // +1 covers any tail

    k_deg  <<<edgeBlocks, NT, 0, stream>>>(dst, deg, E);
    k_node1<<<nodeBlocks, NT, 0, stream>>>(x, deg, dinv, u, N);
    k_edge1<<<edgeBlocks, NT, 0, stream>>>(src, dst, u, agg1, E);
    k_node2<<<nodeBlocks, NT, 0, stream>>>(agg1, u, dinv, W1, b1, W2, q, N);
    k_edge2<<<edgeBlocks, NT, 0, stream>>>(src, dst, q, agg2, E);
    k_node3<<<nodeBlocks, NT, 0, stream>>>(agg2, q, dinv, b2, (float2*)d_out, N);
}

// Round 2
// 368.633 us; speedup vs baseline: 4.2655x; 4.2655x over previous
//
#include <hip/hip_runtime.h>
#include <math.h>

// ---------------------------------------------------------------------------
// Strategy: dst-bucketed aggregation to replace 32M device-scope atomics
// (each costs a 32B write-through at the coherence point ≈ 48ns machine-wide)
// with LDS-private accumulation.
//   Phase 1 : scatter edges into 489 buckets of 1024 nodes each, payload
//             packed u32 = (src<<10) | (dst & 1023). Block-level slot
//             reservation => only ~240k global atomics total.
//   Phase 2a: per-bucket LDS histogram -> deg -> dinv, u = x*dinv   (fused)
//   Phase 2b: per-bucket LDS sum of u[src] -> s1 -> 1->16->2 MLP -> q (fused)
//   Phase 2c: per-bucket LDS float2 sum of q[src] -> log_softmax -> out
// ---------------------------------------------------------------------------

#define NPB 1024            // nodes per bucket (power of two)
#define NPB_SHIFT 10
#define NPB_MASK (NPB - 1)
#define MAXB 512            // max buckets supported by phase-1 LDS arrays
#define P1_THREADS 512
#define P1_EPT 32           // edges per thread, phase 1
#define P2_THREADS 1024     // == NPB, one thread per bucket node in epilogue

// ---------------------------------------------------------------------------
// Phase 1: bucket the edge list by dst >> 10.
// ---------------------------------------------------------------------------
__global__ __launch_bounds__(P1_THREADS) void k_bucket(
    const int* __restrict__ src, const int* __restrict__ dst,
    unsigned int* __restrict__ file, int* __restrict__ ctr,
    int E, int nbucket, int cap)
{
    __shared__ int cnt[MAXB];
    __shared__ int gbase[MAXB];
    __shared__ int rankc[MAXB];
    for (int b = threadIdx.x; b < nbucket; b += P1_THREADS) cnt[b] = 0;
    __syncthreads();

    const int e0 = blockIdx.x * (P1_THREADS * P1_EPT);
#pragma unroll 4
    for (int k = 0; k < P1_EPT; ++k) {
        int e = e0 + k * P1_THREADS + threadIdx.x;
        if (e < E) atomicAdd(&cnt[dst[e] >> NPB_SHIFT], 1);
    }
    __syncthreads();

    for (int b = threadIdx.x; b < nbucket; b += P1_THREADS) {
        rankc[b] = 0;
        int c = cnt[b];
        gbase[b] = c ? atomicAdd(&ctr[b], c) : 0;   // block-level reservation
    }
    __syncthreads();

#pragma unroll 4
    for (int k = 0; k < P1_EPT; ++k) {
        int e = e0 + k * P1_THREADS + threadIdx.x;
        if (e < E) {
            int d = dst[e];                  // 2nd read: L2-hot
            int b = d >> NPB_SHIFT;
            int r = atomicAdd(&rankc[b], 1); // LDS rank bump
            file[(size_t)b * cap + gbase[b] + r] =
                ((unsigned int)src[e] << NPB_SHIFT) | (unsigned int)(d & NPB_MASK);
        }
    }
}

// ---------------------------------------------------------------------------
// Phase 2a: per-bucket degree histogram, then dinv = rsqrt(deg+1), u = x*dinv.
// ---------------------------------------------------------------------------
__global__ __launch_bounds__(P2_THREADS) void k_deg_node1(
    const unsigned int* __restrict__ file, const int* __restrict__ ctr,
    const float* __restrict__ x, float* __restrict__ dinv,
    float* __restrict__ u, int N, int cap)
{
    __shared__ int cnt[NPB];
    const int b = blockIdx.x;
    cnt[threadIdx.x] = 0;
    __syncthreads();
    const int n = ctr[b];
    const unsigned int* f = file + (size_t)b * cap;
    for (int i = threadIdx.x; i < n; i += P2_THREADS)
        atomicAdd(&cnt[f[i] & NPB_MASK], 1);
    __syncthreads();
    const int g = b * NPB + threadIdx.x;
    if (g < N) {
        float dv = rsqrtf((float)(cnt[threadIdx.x] + 1));  // +1 self-loop
        dinv[g] = dv;
        u[g] = x[g] * dv;
    }
}

// ---------------------------------------------------------------------------
// Phase 2b: agg1 = sum u[src] (LDS), s1 = (agg1+u)*dinv, MLP 1->16->2, q out.
// ---------------------------------------------------------------------------
__global__ __launch_bounds__(P2_THREADS) void k_agg1_mlp(
    const unsigned int* __restrict__ file, const int* __restrict__ ctr,
    const float* __restrict__ u, const float* __restrict__ dinv,
    const float* __restrict__ W1, const float* __restrict__ b1,
    const float* __restrict__ W2, float2* __restrict__ q, int N, int cap)
{
    __shared__ float acc[NPB];
    const int b = blockIdx.x;
    acc[threadIdx.x] = 0.f;
    __syncthreads();
    const int n = ctr[b];
    const unsigned int* f = file + (size_t)b * cap;
    for (int i = threadIdx.x; i < n; i += P2_THREADS) {
        unsigned int w = f[i];
        atomicAdd(&acc[w & NPB_MASK], u[w >> NPB_SHIFT]);
    }
    __syncthreads();
    const int g = b * NPB + threadIdx.x;
    if (g < N) {
        float dv = dinv[g];
        float s1 = (acc[threadIdx.x] + u[g]) * dv;
        float c0 = 0.f, c1 = 0.f;
#pragma unroll
        for (int k = 0; k < 16; ++k) {
            float h = fmaxf(fmaf(s1, W1[k], b1[k]), 0.f);
            c0 = fmaf(h, W2[2 * k], c0);
            c1 = fmaf(h, W2[2 * k + 1], c1);
        }
        q[g] = make_float2(c0 * dv, c1 * dv);
    }
}

// ---------------------------------------------------------------------------
// Phase 2c: agg2 = sum q[src] (LDS, 2 planes), + self, *dinv, +b2, logsoftmax.
// ---------------------------------------------------------------------------
__global__ __launch_bounds__(P2_THREADS) void k_agg2_out(
    const unsigned int* __restrict__ file, const int* __restrict__ ctr,
    const float2* __restrict__ q, const float* __restrict__ dinv,
    const float* __restrict__ b2, float2* __restrict__ out, int N, int cap)
{
    __shared__ float a0[NPB];
    __shared__ float a1[NPB];
    const int b = blockIdx.x;
    a0[threadIdx.x] = 0.f;
    a1[threadIdx.x] = 0.f;
    __syncthreads();
    const int n = ctr[b];
    const unsigned int* f = file + (size_t)b * cap;
    for (int i = threadIdx.x; i < n; i += P2_THREADS) {
        unsigned int w = f[i];
        float2 qq = q[w >> NPB_SHIFT];
        int dl = w & NPB_MASK;
        atomicAdd(&a0[dl], qq.x);
        atomicAdd(&a1[dl], qq.y);
    }
    __syncthreads();
    const int g = b * NPB + threadIdx.x;
    if (g < N) {
        float dv = dinv[g];
        float2 qi = q[g];
        float o0 = (a0[threadIdx.x] + qi.x) * dv + b2[0];
        float o1 = (a1[threadIdx.x] + qi.y) * dv + b2[1];
        float m = fmaxf(o0, o1);
        float l = m + logf(expf(o0 - m) + expf(o1 - m));
        out[g] = make_float2(o0 - l, o1 - l);
    }
}

// ===========================================================================
// Fallback path (round-1 kernels) if workspace is too small.
// ===========================================================================
#define NT 256
__global__ __launch_bounds__(NT) void fb_deg(const int* __restrict__ dst,
                                             int* __restrict__ deg, int E) {
    int e = blockIdx.x * blockDim.x + threadIdx.x;
    if (e < E) atomicAdd(&deg[dst[e]], 1);
}
__global__ __launch_bounds__(NT) void fb_node1(const float* __restrict__ x,
                                               const int* __restrict__ deg,
                                               float* __restrict__ dinv,
                                               float* __restrict__ u, int N) {
    int i = blockIdx.x * blockDim.x + threadIdx.x;
    if (i < N) {
        float dv = rsqrtf((float)(deg[i] + 1));
        dinv[i] = dv;
        u[i] = x[i] * dv;
    }
}
__global__ __launch_bounds__(NT) void fb_edge1(const int* __restrict__ src,
                                               const int* __restrict__ dst,
                                               const float* __restrict__ u,
                                               float* __restrict__ agg1, int E) {
    int e = blockIdx.x * blockDim.x + threadIdx.x;
    if (e < E) atomicAdd(&agg1[dst[e]], u[src[e]]);
}
__global__ __launch_bounds__(NT) void fb_node2(const float* __restrict__ agg1,
                                               const float* __restrict__ u,
                                               const float* __restrict__ dinv,
                                               const float* __restrict__ W1,
                                               const float* __restrict__ b1,
                                               const float* __restrict__ W2,
                                               float2* __restrict__ q, int N) {
    int i = blockIdx.x * blockDim.x + threadIdx.x;
    if (i < N) {
        float dv = dinv[i];
        float s1 = (agg1[i] + u[i]) * dv;
        float c0 = 0.f, c1 = 0.f;
#pragma unroll
        for (int k = 0; k < 16; ++k) {
            float h = fmaxf(fmaf(s1, W1[k], b1[k]), 0.f);
            c0 = fmaf(h, W2[2 * k], c0);
            c1 = fmaf(h, W2[2 * k + 1], c1);
        }
        q[i] = make_float2(c0 * dv, c1 * dv);
    }
}
__global__ __launch_bounds__(NT) void fb_edge2(const int* __restrict__ src,
                                               const int* __restrict__ dst,
                                               const float2* __restrict__ q,
                                               float* __restrict__ agg2, int E) {
    int e = blockIdx.x * blockDim.x + threadIdx.x;
    if (e < E) {
        float2 qq = q[src[e]];
        atomicAdd(&agg2[2 * dst[e]], qq.x);
        atomicAdd(&agg2[2 * dst[e] + 1], qq.y);
    }
}
__global__ __launch_bounds__(NT) void fb_node3(const float* __restrict__ agg2,
                                               const float2* __restrict__ q,
                                               const float* __restrict__ dinv,
                                               const float* __restrict__ b2,
                                               float2* __restrict__ out, int N) {
    int i = blockIdx.x * blockDim.x + threadIdx.x;
    if (i < N) {
        float dv = dinv[i];
        float2 qi = q[i];
        float o0 = (agg2[2 * i] + qi.x) * dv + b2[0];
        float o1 = (agg2[2 * i + 1] + qi.y) * dv + b2[1];
        float m = fmaxf(o0, o1);
        float l = m + logf(expf(o0 - m) + expf(o1 - m));
        out[i] = make_float2(o0 - l, o1 - l);
    }
}

// ===========================================================================
extern "C" void kernel_launch(void* const* d_in, const int* in_sizes, int n_in,
                              void* d_out, int out_size, void* d_ws, size_t ws_size,
                              hipStream_t stream) {
    const float* x  = (const float*)d_in[0];
    const int* ei   = (const int*)d_in[1];
    const float* W1 = (const float*)d_in[2];
    const float* b1 = (const float*)d_in[3];
    const float* W2 = (const float*)d_in[4];
    const float* b2 = (const float*)d_in[5];

    const int N = in_sizes[0];
    const int E = in_sizes[1] / 2;
    const int* src = ei;
    const int* dst = ei + E;

    const int nbucket = (N + NPB - 1) / NPB;
    // capacity: mean + generous slack (uniform-random dsts: sigma ~ sqrt(mean))
    const int cap = E / nbucket + 4096;

    // workspace layout (256B-aligned chunks)
    auto align_up = [](size_t v) { return (v + 255) & ~(size_t)255; };
    size_t off_ctr  = 0;
    size_t off_file = align_up((size_t)MAXB * sizeof(int));
    size_t off_dinv = align_up(off_file + (size_t)nbucket * cap * sizeof(unsigned int));
    size_t off_u    = align_up(off_dinv + (size_t)N * sizeof(float));
    size_t off_q    = align_up(off_u + (size_t)N * sizeof(float));
    size_t needed   = off_q + (size_t)N * sizeof(float2);

    char* ws = (char*)d_ws;

    if (nbucket <= MAXB && needed <= ws_size) {
        int*          ctr  = (int*)(ws + off_ctr);
        unsigned int* file = (unsigned int*)(ws + off_file);
        float*        dinv = (float*)(ws + off_dinv);
        float*        u    = (float*)(ws + off_u);
        float2*       q    = (float2*)(ws + off_q);

        hipMemsetAsync(ctr, 0, (size_t)MAXB * sizeof(int), stream);

        const int p1Blocks = (E + P1_THREADS * P1_EPT - 1) / (P1_THREADS * P1_EPT);
        k_bucket   <<<p1Blocks, P1_THREADS, 0, stream>>>(src, dst, file, ctr, E, nbucket, cap);
        k_deg_node1<<<nbucket, P2_THREADS, 0, stream>>>(file, ctr, x, dinv, u, N, cap);
        k_agg1_mlp <<<nbucket, P2_THREADS, 0, stream>>>(file, ctr, u, dinv, W1, b1, W2, q, N, cap);
        k_agg2_out <<<nbucket, P2_THREADS, 0, stream>>>(file, ctr, q, dinv, b2, (float2*)d_out, N, cap);
    } else {
        // fallback: direct-atomic path
        int*    deg  = (int*)   (ws);
        float*  agg1 = (float*) (ws + (size_t)4 * N);
        float*  agg2 = (float*) (ws + (size_t)8 * N);
        float*  dinv = (float*) (ws + (size_t)16 * N);
        float*  u    = (float*) (ws + (size_t)20 * N);
        float2* q    = (float2*)(ws + (size_t)24 * N);
        hipMemsetAsync(ws, 0, (size_t)16 * N, stream);
        const int nodeBlocks = (N + NT - 1) / NT;
        const int edgeBlocks = (E + NT - 1) / NT;
        fb_deg  <<<edgeBlocks, NT, 0, stream>>>(dst, deg, E);
        fb_node1<<<nodeBlocks, NT, 0, stream>>>(x, deg, dinv, u, N);
        fb_edge1<<<edgeBlocks, NT, 0, stream>>>(src, dst, u, agg1, E);
        fb_node2<<<nodeBlocks, NT, 0, stream>>>(agg1, u, dinv, W1, b1, W2, q, N);
        fb_edge2<<<edgeBlocks, NT, 0, stream>>>(src, dst, q, agg2, E);
        fb_node3<<<nodeBlocks, NT, 0, stream>>>(agg2, q, dinv, b2, (float2*)d_out, N);
    }
}

// Round 4
// 307.281 us; speedup vs baseline: 5.1171x; 1.1997x over previous
//
#include <hip/hip_runtime.h>
#include <math.h>

// ---------------------------------------------------------------------------
// Pipeline (all LDS-privatized, no device-scope float atomics):
//   Phase 1 : k_bucket — block-local counting sort of 16384-edge chunks by
//             dst>>10 in LDS, then COALESCED run write-out to a per-bucket
//             file region (global atomic only for per-(block,bucket) base
//             reservation: ~240k atomics total). Payload u32=(src<<10)|dstlo.
//   Phase 2a: per-bucket deg histogram -> dinv = rsqrt(deg+1), u = x*dinv
//   Phase 2b: agg1 = sum u[src] (LDS) -> s1 -> MLP 1->16->2 -> q
//   Phase 2c: agg2 = sum q[src] (LDS float2) -> +self, *dinv, +b2, logsoftmax
// File reads/writes are non-temporal so the 32MB streams don't evict the
// 2-4MB u/q gather arrays from L2.
// NOTE: __builtin_nontemporal_load needs a clang ext_vector_type, not HIP's
// uint4 class — hence uint4v below.
// ---------------------------------------------------------------------------

typedef unsigned int uint4v __attribute__((ext_vector_type(4)));

#define NPB 1024            // nodes per bucket (power of two)
#define NPB_SHIFT 10
#define NPB_MASK (NPB - 1)
#define MAXB 512            // max buckets (prefix-scan width)
#define P1T 512             // phase-1 threads
#define CHUNK 16384         // edges per phase-1 block (fits 64KB LDS)
#define P2_THREADS 1024     // == NPB

// ---------------------------------------------------------------------------
// Phase 1: counting-sort bucketing with coalesced write-out.
// ---------------------------------------------------------------------------
__global__ __launch_bounds__(P1T) void k_bucket(
    const int* __restrict__ src, const int* __restrict__ dst,
    unsigned int* __restrict__ file, int* __restrict__ ctr,
    int E, int nbucket, int cap)
{
    __shared__ unsigned int sorted[CHUNK];   // 64 KB
    __shared__ int cnt[MAXB];
    __shared__ int pre[MAXB + 1];
    __shared__ int gb[MAXB];
    __shared__ int rk[MAXB];

    const int t  = threadIdx.x;
    const int e0 = blockIdx.x * CHUNK;
    const int nE = min(CHUNK, E - e0);

    for (int b = t; b < nbucket; b += P1T) { cnt[b] = 0; rk[b] = 0; }
    __syncthreads();

    // pass 1: bucket histogram
    for (int i = t; i < nE; i += P1T)
        atomicAdd(&cnt[((unsigned)dst[e0 + i]) >> NPB_SHIFT], 1);
    __syncthreads();

    // inclusive Hillis-Steele scan over MAXB entries -> pre[1..], pre[0]=0
    int v = (t < nbucket) ? cnt[t] : 0;
    pre[t + 1] = v;
    if (t == 0) pre[0] = 0;
    __syncthreads();
    for (int off = 1; off < P1T; off <<= 1) {
        int add = (t >= off) ? pre[t + 1 - off] : 0;
        __syncthreads();
        pre[t + 1] += add;
        __syncthreads();
    }

    // reserve global space per (block,bucket)
    for (int b = t; b < nbucket; b += P1T) {
        int c = cnt[b];
        gb[b] = c ? atomicAdd(&ctr[b], c) : 0;
    }
    __syncthreads();

    // pass 2: scatter into LDS in bucket order (dst re-read is L2-hot)
    for (int i = t; i < nE; i += P1T) {
        int d = dst[e0 + i];
        int b = ((unsigned)d) >> NPB_SHIFT;
        unsigned int w = (((unsigned)src[e0 + i]) << NPB_SHIFT) |
                         ((unsigned)d & NPB_MASK);
        int r = atomicAdd(&rk[b], 1);
        sorted[pre[b] + r] = w;
    }
    __syncthreads();

    // pass 3: coalesced write-out; run id via binary search on pre[]
    for (int i = t; i < nE; i += P1T) {
        int lo = 0, hi = nbucket;
        while (hi - lo > 1) {
            int mid = (lo + hi) >> 1;
            if (pre[mid] <= i) lo = mid; else hi = mid;
        }
        __builtin_nontemporal_store(
            sorted[i], &file[(size_t)lo * cap + gb[lo] + (i - pre[lo])]);
    }
}

// ---------------------------------------------------------------------------
// Phase 2a: per-bucket degree histogram -> dinv, u.
// ---------------------------------------------------------------------------
__global__ __launch_bounds__(P2_THREADS) void k_deg_node1(
    const unsigned int* __restrict__ file, const int* __restrict__ ctr,
    const float* __restrict__ x, float* __restrict__ dinv,
    float* __restrict__ u, int N, int cap)
{
    __shared__ int cnt[NPB];
    const int b = blockIdx.x;
    cnt[threadIdx.x] = 0;
    __syncthreads();
    const int n = ctr[b];
    const unsigned int* f = file + (size_t)b * cap;
    const int n4 = n & ~3;
    for (int i = threadIdx.x * 4; i < n4; i += P2_THREADS * 4) {
        uint4v w = __builtin_nontemporal_load((const uint4v*)(f + i));
        atomicAdd(&cnt[w.x & NPB_MASK], 1);
        atomicAdd(&cnt[w.y & NPB_MASK], 1);
        atomicAdd(&cnt[w.z & NPB_MASK], 1);
        atomicAdd(&cnt[w.w & NPB_MASK], 1);
    }
    for (int i = n4 + threadIdx.x; i < n; i += P2_THREADS)
        atomicAdd(&cnt[__builtin_nontemporal_load(f + i) & NPB_MASK], 1);
    __syncthreads();
    const int g = b * NPB + threadIdx.x;
    if (g < N) {
        float dv = rsqrtf((float)(cnt[threadIdx.x] + 1));  // +1 self-loop
        dinv[g] = dv;
        u[g] = x[g] * dv;
    }
}

// ---------------------------------------------------------------------------
// Phase 2b: agg1 = sum u[src] (LDS) -> s1 -> MLP 1->16->2 -> q.
// ---------------------------------------------------------------------------
__global__ __launch_bounds__(P2_THREADS) void k_agg1_mlp(
    const unsigned int* __restrict__ file, const int* __restrict__ ctr,
    const float* __restrict__ u, const float* __restrict__ dinv,
    const float* __restrict__ W1, const float* __restrict__ b1,
    const float* __restrict__ W2, float2* __restrict__ q, int N, int cap)
{
    __shared__ float acc[NPB];
    const int b = blockIdx.x;
    acc[threadIdx.x] = 0.f;
    __syncthreads();
    const int n = ctr[b];
    const unsigned int* f = file + (size_t)b * cap;
    const int n4 = n & ~3;
    for (int i = threadIdx.x * 4; i < n4; i += P2_THREADS * 4) {
        uint4v w = __builtin_nontemporal_load((const uint4v*)(f + i));
        float ux = u[w.x >> NPB_SHIFT];
        float uy = u[w.y >> NPB_SHIFT];
        float uz = u[w.z >> NPB_SHIFT];
        float uw = u[w.w >> NPB_SHIFT];
        atomicAdd(&acc[w.x & NPB_MASK], ux);
        atomicAdd(&acc[w.y & NPB_MASK], uy);
        atomicAdd(&acc[w.z & NPB_MASK], uz);
        atomicAdd(&acc[w.w & NPB_MASK], uw);
    }
    for (int i = n4 + threadIdx.x; i < n; i += P2_THREADS) {
        unsigned int w = __builtin_nontemporal_load(f + i);
        atomicAdd(&acc[w & NPB_MASK], u[w >> NPB_SHIFT]);
    }
    __syncthreads();
    const int g = b * NPB + threadIdx.x;
    if (g < N) {
        float dv = dinv[g];
        float s1 = (acc[threadIdx.x] + u[g]) * dv;
        float c0 = 0.f, c1 = 0.f;
#pragma unroll
        for (int k = 0; k < 16; ++k) {
            float h = fmaxf(fmaf(s1, W1[k], b1[k]), 0.f);
            c0 = fmaf(h, W2[2 * k], c0);
            c1 = fmaf(h, W2[2 * k + 1], c1);
        }
        q[g] = make_float2(c0 * dv, c1 * dv);
    }
}

// ---------------------------------------------------------------------------
// Phase 2c: agg2 = sum q[src] (LDS x2) -> +self, *dinv, +b2, log_softmax.
// ---------------------------------------------------------------------------
__global__ __launch_bounds__(P2_THREADS) void k_agg2_out(
    const unsigned int* __restrict__ file, const int* __restrict__ ctr,
    const float2* __restrict__ q, const float* __restrict__ dinv,
    const float* __restrict__ b2, float2* __restrict__ out, int N, int cap)
{
    __shared__ float a0[NPB];
    __shared__ float a1[NPB];
    const int b = blockIdx.x;
    a0[threadIdx.x] = 0.f;
    a1[threadIdx.x] = 0.f;
    __syncthreads();
    const int n = ctr[b];
    const unsigned int* f = file + (size_t)b * cap;
    const int n4 = n & ~3;
    for (int i = threadIdx.x * 4; i < n4; i += P2_THREADS * 4) {
        uint4v w = __builtin_nontemporal_load((const uint4v*)(f + i));
        float2 q0 = q[w.x >> NPB_SHIFT];
        float2 q1 = q[w.y >> NPB_SHIFT];
        float2 q2 = q[w.z >> NPB_SHIFT];
        float2 q3 = q[w.w >> NPB_SHIFT];
        atomicAdd(&a0[w.x & NPB_MASK], q0.x);
        atomicAdd(&a1[w.x & NPB_MASK], q0.y);
        atomicAdd(&a0[w.y & NPB_MASK], q1.x);
        atomicAdd(&a1[w.y & NPB_MASK], q1.y);
        atomicAdd(&a0[w.z & NPB_MASK], q2.x);
        atomicAdd(&a1[w.z & NPB_MASK], q2.y);
        atomicAdd(&a0[w.w & NPB_MASK], q3.x);
        atomicAdd(&a1[w.w & NPB_MASK], q3.y);
    }
    for (int i = n4 + threadIdx.x; i < n; i += P2_THREADS) {
        unsigned int w = __builtin_nontemporal_load(f + i);
        float2 qq = q[w >> NPB_SHIFT];
        atomicAdd(&a0[w & NPB_MASK], qq.x);
        atomicAdd(&a1[w & NPB_MASK], qq.y);
    }
    __syncthreads();
    const int g = b * NPB + threadIdx.x;
    if (g < N) {
        float dv = dinv[g];
        float2 qi = q[g];
        float o0 = (a0[threadIdx.x] + qi.x) * dv + b2[0];
        float o1 = (a1[threadIdx.x] + qi.y) * dv + b2[1];
        float m = fmaxf(o0, o1);
        float l = m + logf(expf(o0 - m) + expf(o1 - m));
        out[g] = make_float2(o0 - l, o1 - l);
    }
}

// ===========================================================================
// Fallback path (direct-atomic) if workspace is too small.
// ===========================================================================
#define NT 256
__global__ __launch_bounds__(NT) void fb_deg(const int* __restrict__ dst,
                                             int* __restrict__ deg, int E) {
    int e = blockIdx.x * blockDim.x + threadIdx.x;
    if (e < E) atomicAdd(&deg[dst[e]], 1);
}
__global__ __launch_bounds__(NT) void fb_node1(const float* __restrict__ x,
                                               const int* __restrict__ deg,
                                               float* __restrict__ dinv,
                                               float* __restrict__ u, int N) {
    int i = blockIdx.x * blockDim.x + threadIdx.x;
    if (i < N) {
        float dv = rsqrtf((float)(deg[i] + 1));
        dinv[i] = dv;
        u[i] = x[i] * dv;
    }
}
__global__ __launch_bounds__(NT) void fb_edge1(const int* __restrict__ src,
                                               const int* __restrict__ dst,
                                               const float* __restrict__ u,
                                               float* __restrict__ agg1, int E) {
    int e = blockIdx.x * blockDim.x + threadIdx.x;
    if (e < E) atomicAdd(&agg1[dst[e]], u[src[e]]);
}
__global__ __launch_bounds__(NT) void fb_node2(const float* __restrict__ agg1,
                                               const float* __restrict__ u,
                                               const float* __restrict__ dinv,
                                               const float* __restrict__ W1,
                                               const float* __restrict__ b1,
                                               const float* __restrict__ W2,
                                               float2* __restrict__ q, int N) {
    int i = blockIdx.x * blockDim.x + threadIdx.x;
    if (i < N) {
        float dv = dinv[i];
        float s1 = (agg1[i] + u[i]) * dv;
        float c0 = 0.f, c1 = 0.f;
#pragma unroll
        for (int k = 0; k < 16; ++k) {
            float h = fmaxf(fmaf(s1, W1[k], b1[k]), 0.f);
            c0 = fmaf(h, W2[2 * k], c0);
            c1 = fmaf(h, W2[2 * k + 1], c1);
        }
        q[i] = make_float2(c0 * dv, c1 * dv);
    }
}
__global__ __launch_bounds__(NT) void fb_edge2(const int* __restrict__ src,
                                               const int* __restrict__ dst,
                                               const float2* __restrict__ q,
                                               float* __restrict__ agg2, int E) {
    int e = blockIdx.x * blockDim.x + threadIdx.x;
    if (e < E) {
        float2 qq = q[src[e]];
        atomicAdd(&agg2[2 * dst[e]], qq.x);
        atomicAdd(&agg2[2 * dst[e] + 1], qq.y);
    }
}
__global__ __launch_bounds__(NT) void fb_node3(const float* __restrict__ agg2,
                                               const float2* __restrict__ q,
                                               const float* __restrict__ dinv,
                                               const float* __restrict__ b2,
                                               float2* __restrict__ out, int N) {
    int i = blockIdx.x * blockDim.x + threadIdx.x;
    if (i < N) {
        float dv = dinv[i];
        float2 qi = q[i];
        float o0 = (agg2[2 * i] + qi.x) * dv + b2[0];
        float o1 = (agg2[2 * i + 1] + qi.y) * dv + b2[1];
        float m = fmaxf(o0, o1);
        float l = m + logf(expf(o0 - m) + expf(o1 - m));
        out[i] = make_float2(o0 - l, o1 - l);
    }
}

// ===========================================================================
extern "C" void kernel_launch(void* const* d_in, const int* in_sizes, int n_in,
                              void* d_out, int out_size, void* d_ws, size_t ws_size,
                              hipStream_t stream) {
    const float* x  = (const float*)d_in[0];
    const int* ei   = (const int*)d_in[1];
    const float* W1 = (const float*)d_in[2];
    const float* b1 = (const float*)d_in[3];
    const float* W2 = (const float*)d_in[4];
    const float* b2 = (const float*)d_in[5];

    const int N = in_sizes[0];
    const int E = in_sizes[1] / 2;
    const int* src = ei;
    const int* dst = ei + E;

    const int nbucket = (N + NPB - 1) / NPB;
    // capacity: mean + slack (uniform dsts: sd ~ sqrt(mean)); 64-aligned so
    // every bucket base is 16B-aligned for uint4v loads.
    const int cap = ((E / nbucket + 4096) + 63) & ~63;

    auto align_up = [](size_t v) { return (v + 255) & ~(size_t)255; };
    size_t off_ctr  = 0;
    size_t off_file = align_up((size_t)MAXB * sizeof(int));
    size_t off_dinv = align_up(off_file + (size_t)nbucket * cap * sizeof(unsigned int));
    size_t off_u    = align_up(off_dinv + (size_t)N * sizeof(float));
    size_t off_q    = align_up(off_u + (size_t)N * sizeof(float));
    size_t needed   = off_q + (size_t)N * sizeof(float2);

    char* ws = (char*)d_ws;

    if (nbucket <= MAXB && needed <= ws_size) {
        int*          ctr  = (int*)(ws + off_ctr);
        unsigned int* file = (unsigned int*)(ws + off_file);
        float*        dinv = (float*)(ws + off_dinv);
        float*        u    = (float*)(ws + off_u);
        float2*       q    = (float2*)(ws + off_q);

        (void)hipMemsetAsync(ctr, 0, (size_t)MAXB * sizeof(int), stream);

        const int p1Blocks = (E + CHUNK - 1) / CHUNK;
        k_bucket   <<<p1Blocks, P1T, 0, stream>>>(src, dst, file, ctr, E, nbucket, cap);
        k_deg_node1<<<nbucket, P2_THREADS, 0, stream>>>(file, ctr, x, dinv, u, N, cap);
        k_agg1_mlp <<<nbucket, P2_THREADS, 0, stream>>>(file, ctr, u, dinv, W1, b1, W2, q, N, cap);
        k_agg2_out <<<nbucket, P2_THREADS, 0, stream>>>(file, ctr, q, dinv, b2, (float2*)d_out, N, cap);
    } else {
        int*    deg  = (int*)   (ws);
        float*  agg1 = (float*) (ws + (size_t)4 * N);
        float*  agg2 = (float*) (ws + (size_t)8 * N);
        float*  dinv = (float*) (ws + (size_t)16 * N);
        float*  u    = (float*) (ws + (size_t)20 * N);
        float2* q    = (float2*)(ws + (size_t)24 * N);
        (void)hipMemsetAsync(ws, 0, (size_t)16 * N, stream);
        const int nodeBlocks = (N + NT - 1) / NT;
        const int edgeBlocks = (E + NT - 1) / NT;
        fb_deg  <<<edgeBlocks, NT, 0, stream>>>(dst, deg, E);
        fb_node1<<<nodeBlocks, NT, 0, stream>>>(x, deg, dinv, u, N);
        fb_edge1<<<edgeBlocks, NT, 0, stream>>>(src, dst, u, agg1, E);
        fb_node2<<<nodeBlocks, NT, 0, stream>>>(agg1, u, dinv, W1, b1, W2, q, N);
        fb_edge2<<<edgeBlocks, NT, 0, stream>>>(src, dst, q, agg2, E);
        fb_node3<<<nodeBlocks, NT, 0, stream>>>(agg2, q, dinv, b2, (float2*)d_out, N);
    }
}

// Round 5
// 285.142 us; speedup vs baseline: 5.5144x; 1.0776x over previous
//
#include <hip/hip_runtime.h>
#include <math.h>

// ---------------------------------------------------------------------------
// Pipeline (all LDS-privatized, no device-scope float atomics):
//   Phase 1 : k_bucket — block-local counting sort of 16384-edge chunks by
//             dst>>10 in LDS (dst cached in registers across passes), then
//             coalesced run write-out to per-bucket file regions.
//   Phase 2a: per-bucket deg histogram -> dinv = rsqrt(deg+1), u = x*dinv
//   Phase 2b: agg1 = sum u[src] (LDS) -> s1 -> MLP 1->16->2 -> q
//   Phase 2c: agg2 = sum q[src] (LDS float2) -> +self, *dinv, +b2, logsoftmax
// Phase-2 loops are unrolled x8 with strided uint4 file loads so each lane
// keeps ~8 scattered gathers in flight (Little's law: prior version had ~4
// outstanding -> 0.34 req/cyc/CU; gathers were the bottleneck, not BW).
// ---------------------------------------------------------------------------

typedef unsigned int uint4v __attribute__((ext_vector_type(4)));

#define NPB 1024            // nodes per bucket (power of two)
#define NPB_SHIFT 10
#define NPB_MASK (NPB - 1)
#define MAXB 512            // max buckets (prefix-scan width)
#define P1T 512             // phase-1 threads
#define CHUNK 16384         // edges per phase-1 block (64KB LDS staging)
#define P2_THREADS 1024     // == NPB

#define NTL4(p) __builtin_nontemporal_load((const uint4v*)(p))

// ---------------------------------------------------------------------------
// Phase 1: counting-sort bucketing with coalesced write-out.
// ---------------------------------------------------------------------------
__global__ __launch_bounds__(P1T, 4) void k_bucket(
    const int* __restrict__ src, const int* __restrict__ dst,
    unsigned int* __restrict__ file, int* __restrict__ ctr,
    int E, int nbucket, int cap)
{
    __shared__ unsigned int sorted[CHUNK];   // 64 KB
    __shared__ int cnt[MAXB];
    __shared__ int pre[MAXB + 1];
    __shared__ int gb[MAXB];
    __shared__ int rk[MAXB];

    const int t  = threadIdx.x;
    const int e0 = blockIdx.x * CHUNK;
    const int nE = min(CHUNK, E - e0);

    for (int b = t; b < MAXB; b += P1T) { cnt[b] = 0; rk[b] = 0; }
    __syncthreads();

    const bool full = (nE == CHUNK);
    int4 dc[8];   // register-cached dst values (full blocks only)

    // ---- pass 1: bucket histogram ----
    if (full) {
        const int4* d4 = (const int4*)(dst + e0);
#pragma unroll
        for (int k = 0; k < 8; ++k) dc[k] = d4[t + k * P1T];
#pragma unroll
        for (int k = 0; k < 8; ++k) {
            atomicAdd(&cnt[((unsigned)dc[k].x) >> NPB_SHIFT], 1);
            atomicAdd(&cnt[((unsigned)dc[k].y) >> NPB_SHIFT], 1);
            atomicAdd(&cnt[((unsigned)dc[k].z) >> NPB_SHIFT], 1);
            atomicAdd(&cnt[((unsigned)dc[k].w) >> NPB_SHIFT], 1);
        }
    } else {
        for (int i = t; i < nE; i += P1T)
            atomicAdd(&cnt[((unsigned)dst[e0 + i]) >> NPB_SHIFT], 1);
    }
    __syncthreads();

    // ---- inclusive Hillis-Steele scan: pre[0]=0, pre[b+1]=sum cnt[0..b] ----
    int v = (t < nbucket) ? cnt[t] : 0;
    pre[t + 1] = v;
    if (t == 0) pre[0] = 0;
    __syncthreads();
    for (int off = 1; off < P1T; off <<= 1) {
        int add = (t >= off) ? pre[t + 1 - off] : 0;
        __syncthreads();
        pre[t + 1] += add;
        __syncthreads();
    }

    // ---- reserve global space per (block,bucket) ----
    for (int b = t; b < nbucket; b += P1T) {
        int c = cnt[b];
        gb[b] = c ? atomicAdd(&ctr[b], c) : 0;
    }
    __syncthreads();

    // ---- pass 2: scatter into LDS in bucket order ----
    if (full) {
        const int4* s4 = (const int4*)(src + e0);
#pragma unroll
        for (int k = 0; k < 8; ++k) {
            int4 s = s4[t + k * P1T];
            int4 d = dc[k];
            {
                int b = ((unsigned)d.x) >> NPB_SHIFT;
                int r = atomicAdd(&rk[b], 1);
                sorted[pre[b] + r] = (((unsigned)s.x) << NPB_SHIFT) | ((unsigned)d.x & NPB_MASK);
            }
            {
                int b = ((unsigned)d.y) >> NPB_SHIFT;
                int r = atomicAdd(&rk[b], 1);
                sorted[pre[b] + r] = (((unsigned)s.y) << NPB_SHIFT) | ((unsigned)d.y & NPB_MASK);
            }
            {
                int b = ((unsigned)d.z) >> NPB_SHIFT;
                int r = atomicAdd(&rk[b], 1);
                sorted[pre[b] + r] = (((unsigned)s.z) << NPB_SHIFT) | ((unsigned)d.z & NPB_MASK);
            }
            {
                int b = ((unsigned)d.w) >> NPB_SHIFT;
                int r = atomicAdd(&rk[b], 1);
                sorted[pre[b] + r] = (((unsigned)s.w) << NPB_SHIFT) | ((unsigned)d.w & NPB_MASK);
            }
        }
    } else {
        for (int i = t; i < nE; i += P1T) {
            int d = dst[e0 + i];
            int b = ((unsigned)d) >> NPB_SHIFT;
            unsigned int w = (((unsigned)src[e0 + i]) << NPB_SHIFT) |
                             ((unsigned)d & NPB_MASK);
            int r = atomicAdd(&rk[b], 1);
            sorted[pre[b] + r] = w;
        }
    }
    __syncthreads();

    // ---- pass 3: coalesced write-out (consecutive lanes -> consecutive
    //      addresses within a run); run id via binary search on pre[] ----
    for (int i = t; i < nE; i += P1T) {
        int lo = 0, hi = nbucket;
        while (hi - lo > 1) {
            int mid = (lo + hi) >> 1;
            if (pre[mid] <= i) lo = mid; else hi = mid;
        }
        __builtin_nontemporal_store(
            sorted[i], &file[(size_t)lo * cap + gb[lo] + (i - pre[lo])]);
    }
}

// ---------------------------------------------------------------------------
// Phase 2a: per-bucket degree histogram -> dinv, u.
// ---------------------------------------------------------------------------
__global__ __launch_bounds__(P2_THREADS, 8) void k_deg_node1(
    const unsigned int* __restrict__ file, const int* __restrict__ ctr,
    const float* __restrict__ x, float* __restrict__ dinv,
    float* __restrict__ u, int N, int cap)
{
    __shared__ int cnt[NPB];
    const int b = blockIdx.x;
    cnt[threadIdx.x] = 0;
    __syncthreads();
    const int n = ctr[b];
    const unsigned int* f = file + (size_t)b * cap;
    const int T4 = P2_THREADS * 4;
    int i = threadIdx.x * 4;
    for (; i + T4 + 3 < n; i += 2 * T4) {
        uint4v w0 = NTL4(f + i);
        uint4v w1 = NTL4(f + i + T4);
        atomicAdd(&cnt[w0.x & NPB_MASK], 1);
        atomicAdd(&cnt[w0.y & NPB_MASK], 1);
        atomicAdd(&cnt[w0.z & NPB_MASK], 1);
        atomicAdd(&cnt[w0.w & NPB_MASK], 1);
        atomicAdd(&cnt[w1.x & NPB_MASK], 1);
        atomicAdd(&cnt[w1.y & NPB_MASK], 1);
        atomicAdd(&cnt[w1.z & NPB_MASK], 1);
        atomicAdd(&cnt[w1.w & NPB_MASK], 1);
    }
    for (; i + 3 < n; i += T4) {
        uint4v w = NTL4(f + i);
        atomicAdd(&cnt[w.x & NPB_MASK], 1);
        atomicAdd(&cnt[w.y & NPB_MASK], 1);
        atomicAdd(&cnt[w.z & NPB_MASK], 1);
        atomicAdd(&cnt[w.w & NPB_MASK], 1);
    }
    for (int j = (n & ~3) + threadIdx.x; j < n; j += P2_THREADS)
        atomicAdd(&cnt[__builtin_nontemporal_load(f + j) & NPB_MASK], 1);
    __syncthreads();
    const int g = b * NPB + threadIdx.x;
    if (g < N) {
        float dv = rsqrtf((float)(cnt[threadIdx.x] + 1));  // +1 self-loop
        dinv[g] = dv;
        u[g] = x[g] * dv;
    }
}

// ---------------------------------------------------------------------------
// Phase 2b: agg1 = sum u[src] (LDS) -> s1 -> MLP 1->16->2 -> q.
// ---------------------------------------------------------------------------
__global__ __launch_bounds__(P2_THREADS, 8) void k_agg1_mlp(
    const unsigned int* __restrict__ file, const int* __restrict__ ctr,
    const float* __restrict__ u, const float* __restrict__ dinv,
    const float* __restrict__ W1, const float* __restrict__ b1,
    const float* __restrict__ W2, float2* __restrict__ q, int N, int cap)
{
    __shared__ float acc[NPB];
    const int b = blockIdx.x;
    acc[threadIdx.x] = 0.f;
    __syncthreads();
    const int n = ctr[b];
    const unsigned int* f = file + (size_t)b * cap;
    const int T4 = P2_THREADS * 4;
    int i = threadIdx.x * 4;
    for (; i + T4 + 3 < n; i += 2 * T4) {
        uint4v w0 = NTL4(f + i);
        uint4v w1 = NTL4(f + i + T4);
        float v0 = u[w0.x >> NPB_SHIFT];
        float v1 = u[w0.y >> NPB_SHIFT];
        float v2 = u[w0.z >> NPB_SHIFT];
        float v3 = u[w0.w >> NPB_SHIFT];
        float v4 = u[w1.x >> NPB_SHIFT];
        float v5 = u[w1.y >> NPB_SHIFT];
        float v6 = u[w1.z >> NPB_SHIFT];
        float v7 = u[w1.w >> NPB_SHIFT];
        atomicAdd(&acc[w0.x & NPB_MASK], v0);
        atomicAdd(&acc[w0.y & NPB_MASK], v1);
        atomicAdd(&acc[w0.z & NPB_MASK], v2);
        atomicAdd(&acc[w0.w & NPB_MASK], v3);
        atomicAdd(&acc[w1.x & NPB_MASK], v4);
        atomicAdd(&acc[w1.y & NPB_MASK], v5);
        atomicAdd(&acc[w1.z & NPB_MASK], v6);
        atomicAdd(&acc[w1.w & NPB_MASK], v7);
    }
    for (; i + 3 < n; i += T4) {
        uint4v w = NTL4(f + i);
        float v0 = u[w.x >> NPB_SHIFT];
        float v1 = u[w.y >> NPB_SHIFT];
        float v2 = u[w.z >> NPB_SHIFT];
        float v3 = u[w.w >> NPB_SHIFT];
        atomicAdd(&acc[w.x & NPB_MASK], v0);
        atomicAdd(&acc[w.y & NPB_MASK], v1);
        atomicAdd(&acc[w.z & NPB_MASK], v2);
        atomicAdd(&acc[w.w & NPB_MASK], v3);
    }
    for (int j = (n & ~3) + threadIdx.x; j < n; j += P2_THREADS) {
        unsigned int w = __builtin_nontemporal_load(f + j);
        atomicAdd(&acc[w & NPB_MASK], u[w >> NPB_SHIFT]);
    }
    __syncthreads();
    const int g = b * NPB + threadIdx.x;
    if (g < N) {
        float dv = dinv[g];
        float s1 = (acc[threadIdx.x] + u[g]) * dv;
        float c0 = 0.f, c1 = 0.f;
#pragma unroll
        for (int k = 0; k < 16; ++k) {
            float h = fmaxf(fmaf(s1, W1[k], b1[k]), 0.f);
            c0 = fmaf(h, W2[2 * k], c0);
            c1 = fmaf(h, W2[2 * k + 1], c1);
        }
        q[g] = make_float2(c0 * dv, c1 * dv);
    }
}

// ---------------------------------------------------------------------------
// Phase 2c: agg2 = sum q[src] (LDS x2) -> +self, *dinv, +b2, log_softmax.
// ---------------------------------------------------------------------------
__global__ __launch_bounds__(P2_THREADS, 8) void k_agg2_out(
    const unsigned int* __restrict__ file, const int* __restrict__ ctr,
    const float2* __restrict__ q, const float* __restrict__ dinv,
    const float* __restrict__ b2, float2* __restrict__ out, int N, int cap)
{
    __shared__ float a0[NPB];
    __shared__ float a1[NPB];
    const int b = blockIdx.x;
    a0[threadIdx.x] = 0.f;
    a1[threadIdx.x] = 0.f;
    __syncthreads();
    const int n = ctr[b];
    const unsigned int* f = file + (size_t)b * cap;
    const int T4 = P2_THREADS * 4;
    int i = threadIdx.x * 4;
    for (; i + T4 + 3 < n; i += 2 * T4) {
        uint4v w0 = NTL4(f + i);
        uint4v w1 = NTL4(f + i + T4);
        float2 g0 = q[w0.x >> NPB_SHIFT];
        float2 g1 = q[w0.y >> NPB_SHIFT];
        float2 g2 = q[w0.z >> NPB_SHIFT];
        float2 g3 = q[w0.w >> NPB_SHIFT];
        float2 g4 = q[w1.x >> NPB_SHIFT];
        float2 g5 = q[w1.y >> NPB_SHIFT];
        float2 g6 = q[w1.z >> NPB_SHIFT];
        float2 g7 = q[w1.w >> NPB_SHIFT];
        atomicAdd(&a0[w0.x & NPB_MASK], g0.x);
        atomicAdd(&a1[w0.x & NPB_MASK], g0.y);
        atomicAdd(&a0[w0.y & NPB_MASK], g1.x);
        atomicAdd(&a1[w0.y & NPB_MASK], g1.y);
        atomicAdd(&a0[w0.z & NPB_MASK], g2.x);
        atomicAdd(&a1[w0.z & NPB_MASK], g2.y);
        atomicAdd(&a0[w0.w & NPB_MASK], g3.x);
        atomicAdd(&a1[w0.w & NPB_MASK], g3.y);
        atomicAdd(&a0[w1.x & NPB_MASK], g4.x);
        atomicAdd(&a1[w1.x & NPB_MASK], g4.y);
        atomicAdd(&a0[w1.y & NPB_MASK], g5.x);
        atomicAdd(&a1[w1.y & NPB_MASK], g5.y);
        atomicAdd(&a0[w1.z & NPB_MASK], g6.x);
        atomicAdd(&a1[w1.z & NPB_MASK], g6.y);
        atomicAdd(&a0[w1.w & NPB_MASK], g7.x);
        atomicAdd(&a1[w1.w & NPB_MASK], g7.y);
    }
    for (; i + 3 < n; i += T4) {
        uint4v w = NTL4(f + i);
        float2 g0 = q[w.x >> NPB_SHIFT];
        float2 g1 = q[w.y >> NPB_SHIFT];
        float2 g2 = q[w.z >> NPB_SHIFT];
        float2 g3 = q[w.w >> NPB_SHIFT];
        atomicAdd(&a0[w.x & NPB_MASK], g0.x);
        atomicAdd(&a1[w.x & NPB_MASK], g0.y);
        atomicAdd(&a0[w.y & NPB_MASK], g1.x);
        atomicAdd(&a1[w.y & NPB_MASK], g1.y);
        atomicAdd(&a0[w.z & NPB_MASK], g2.x);
        atomicAdd(&a1[w.z & NPB_MASK], g2.y);
        atomicAdd(&a0[w.w & NPB_MASK], g3.x);
        atomicAdd(&a1[w.w & NPB_MASK], g3.y);
    }
    for (int j = (n & ~3) + threadIdx.x; j < n; j += P2_THREADS) {
        unsigned int w = __builtin_nontemporal_load(f + j);
        float2 qq = q[w >> NPB_SHIFT];
        atomicAdd(&a0[w & NPB_MASK], qq.x);
        atomicAdd(&a1[w & NPB_MASK], qq.y);
    }
    __syncthreads();
    const int g = b * NPB + threadIdx.x;
    if (g < N) {
        float dv = dinv[g];
        float2 qi = q[g];
        float o0 = (a0[threadIdx.x] + qi.x) * dv + b2[0];
        float o1 = (a1[threadIdx.x] + qi.y) * dv + b2[1];
        float m = fmaxf(o0, o1);
        float l = m + logf(expf(o0 - m) + expf(o1 - m));
        out[g] = make_float2(o0 - l, o1 - l);
    }
}

// ===========================================================================
// Fallback path (direct-atomic) if workspace is too small.
// ===========================================================================
#define NT 256
__global__ __launch_bounds__(NT) void fb_deg(const int* __restrict__ dst,
                                             int* __restrict__ deg, int E) {
    int e = blockIdx.x * blockDim.x + threadIdx.x;
    if (e < E) atomicAdd(&deg[dst[e]], 1);
}
__global__ __launch_bounds__(NT) void fb_node1(const float* __restrict__ x,
                                               const int* __restrict__ deg,
                                               float* __restrict__ dinv,
                                               float* __restrict__ u, int N) {
    int i = blockIdx.x * blockDim.x + threadIdx.x;
    if (i < N) {
        float dv = rsqrtf((float)(deg[i] + 1));
        dinv[i] = dv;
        u[i] = x[i] * dv;
    }
}
__global__ __launch_bounds__(NT) void fb_edge1(const int* __restrict__ src,
                                               const int* __restrict__ dst,
                                               const float* __restrict__ u,
                                               float* __restrict__ agg1, int E) {
    int e = blockIdx.x * blockDim.x + threadIdx.x;
    if (e < E) atomicAdd(&agg1[dst[e]], u[src[e]]);
}
__global__ __launch_bounds__(NT) void fb_node2(const float* __restrict__ agg1,
                                               const float* __restrict__ u,
                                               const float* __restrict__ dinv,
                                               const float* __restrict__ W1,
                                               const float* __restrict__ b1,
                                               const float* __restrict__ W2,
                                               float2* __restrict__ q, int N) {
    int i = blockIdx.x * blockDim.x + threadIdx.x;
    if (i < N) {
        float dv = dinv[i];
        float s1 = (agg1[i] + u[i]) * dv;
        float c0 = 0.f, c1 = 0.f;
#pragma unroll
        for (int k = 0; k < 16; ++k) {
            float h = fmaxf(fmaf(s1, W1[k], b1[k]), 0.f);
            c0 = fmaf(h, W2[2 * k], c0);
            c1 = fmaf(h, W2[2 * k + 1], c1);
        }
        q[i] = make_float2(c0 * dv, c1 * dv);
    }
}
__global__ __launch_bounds__(NT) void fb_edge2(const int* __restrict__ src,
                                               const int* __restrict__ dst,
                                               const float2* __restrict__ q,
                                               float* __restrict__ agg2, int E) {
    int e = blockIdx.x * blockDim.x + threadIdx.x;
    if (e < E) {
        float2 qq = q[src[e]];
        atomicAdd(&agg2[2 * dst[e]], qq.x);
        atomicAdd(&agg2[2 * dst[e] + 1], qq.y);
    }
}
__global__ __launch_bounds__(NT) void fb_node3(const float* __restrict__ agg2,
                                               const float2* __restrict__ q,
                                               const float* __restrict__ dinv,
                                               const float* __restrict__ b2,
                                               float2* __restrict__ out, int N) {
    int i = blockIdx.x * blockDim.x + threadIdx.x;
    if (i < N) {
        float dv = dinv[i];
        float2 qi = q[i];
        float o0 = (agg2[2 * i] + qi.x) * dv + b2[0];
        float o1 = (agg2[2 * i + 1] + qi.y) * dv + b2[1];
        float m = fmaxf(o0, o1);
        float l = m + logf(expf(o0 - m) + expf(o1 - m));
        out[i] = make_float2(o0 - l, o1 - l);
    }
}

// ===========================================================================
extern "C" void kernel_launch(void* const* d_in, const int* in_sizes, int n_in,
                              void* d_out, int out_size, void* d_ws, size_t ws_size,
                              hipStream_t stream) {
    const float* x  = (const float*)d_in[0];
    const int* ei   = (const int*)d_in[1];
    const float* W1 = (const float*)d_in[2];
    const float* b1 = (const float*)d_in[3];
    const float* W2 = (const float*)d_in[4];
    const float* b2 = (const float*)d_in[5];

    const int N = in_sizes[0];
    const int E = in_sizes[1] / 2;
    const int* src = ei;
    const int* dst = ei + E;

    const int nbucket = (N + NPB - 1) / NPB;
    // capacity: mean + slack (uniform dsts: sd ~ sqrt(mean)); 64-aligned so
    // every bucket base stays 16B-aligned for uint4v loads.
    const int cap = ((E / nbucket + 4096) + 63) & ~63;

    auto align_up = [](size_t v) { return (v + 255) & ~(size_t)255; };
    size_t off_ctr  = 0;
    size_t off_file = align_up((size_t)MAXB * sizeof(int));
    size_t off_dinv = align_up(off_file + (size_t)nbucket * cap * sizeof(unsigned int));
    size_t off_u    = align_up(off_dinv + (size_t)N * sizeof(float));
    size_t off_q    = align_up(off_u + (size_t)N * sizeof(float));
    size_t needed   = off_q + (size_t)N * sizeof(float2);

    char* ws = (char*)d_ws;

    if (nbucket <= MAXB && needed <= ws_size) {
        int*          ctr  = (int*)(ws + off_ctr);
        unsigned int* file = (unsigned int*)(ws + off_file);
        float*        dinv = (float*)(ws + off_dinv);
        float*        u    = (float*)(ws + off_u);
        float2*       q    = (float2*)(ws + off_q);

        (void)hipMemsetAsync(ctr, 0, (size_t)MAXB * sizeof(int), stream);

        const int p1Blocks = (E + CHUNK - 1) / CHUNK;
        k_bucket   <<<p1Blocks, P1T, 0, stream>>>(src, dst, file, ctr, E, nbucket, cap);
        k_deg_node1<<<nbucket, P2_THREADS, 0, stream>>>(file, ctr, x, dinv, u, N, cap);
        k_agg1_mlp <<<nbucket, P2_THREADS, 0, stream>>>(file, ctr, u, dinv, W1, b1, W2, q, N, cap);
        k_agg2_out <<<nbucket, P2_THREADS, 0, stream>>>(file, ctr, q, dinv, b2, (float2*)d_out, N, cap);
    } else {
        int*    deg  = (int*)   (ws);
        float*  agg1 = (float*) (ws + (size_t)4 * N);
        float*  agg2 = (float*) (ws + (size_t)8 * N);
        float*  dinv = (float*) (ws + (size_t)16 * N);
        float*  u    = (float*) (ws + (size_t)20 * N);
        float2* q    = (float2*)(ws + (size_t)24 * N);
        (void)hipMemsetAsync(ws, 0, (size_t)16 * N, stream);
        const int nodeBlocks = (N + NT - 1) / NT;
        const int edgeBlocks = (E + NT - 1) / NT;
        fb_deg  <<<edgeBlocks, NT, 0, stream>>>(dst, deg, E);
        fb_node1<<<nodeBlocks, NT, 0, stream>>>(x, deg, dinv, u, N);
        fb_edge1<<<edgeBlocks, NT, 0, stream>>>(src, dst, u, agg1, E);
        fb_node2<<<nodeBlocks, NT, 0, stream>>>(agg1, u, dinv, W1, b1, W2, q, N);
        fb_edge2<<<edgeBlocks, NT, 0, stream>>>(src, dst, q, agg2, E);
        fb_node3<<<nodeBlocks, NT, 0, stream>>>(agg2, q, dinv, b2, (float2*)d_out, N);
    }
}

// Round 6
// 279.768 us; speedup vs baseline: 5.6203x; 1.0192x over previous
//
#include <hip/hip_runtime.h>
#include <math.h>

// ---------------------------------------------------------------------------
// Pipeline (LDS-privatized aggregation; gather tables compressed to bf16 so
// they stay resident in the 4MB per-XCD L2 — round-5 analysis showed the 8M
// random 8B gathers each pulled a 64B line from L3 (~512MB @ ~5.4TB/s), an
// Infinity-Cache BW wall that ILP could not fix):
//   Phase 1 : k_bucket — LDS counting sort of 16384-edge chunks by dst>>10,
//             per-wave run write-out (no binary search), coalesced stores.
//   Phase 2a: per-bucket deg histogram -> dinv(f32), u = bf16(x*dinv)  [1MB]
//   Phase 2b: agg1 = sum u[src] (LDS) -> s1 -> MLP 1->16->2 -> q packed
//             2xbf16 in u32                                            [2MB]
//   Phase 2c: agg2 = sum unpack(q[src]) (LDS f32 x2) -> +self, *dinv, +b2,
//             log_softmax (f32 out)
// ---------------------------------------------------------------------------

typedef unsigned int uint4v __attribute__((ext_vector_type(4)));

#define NPB 1024            // nodes per bucket (power of two)
#define NPB_SHIFT 10
#define NPB_MASK (NPB - 1)
#define MAXB 512            // max buckets (prefix-scan width)
#define P1T 512             // phase-1 threads
#define CHUNK 16384         // edges per phase-1 block (64KB LDS staging)
#define P2_THREADS 1024     // == NPB

#define NTL4(p) __builtin_nontemporal_load((const uint4v*)(p))

__device__ __forceinline__ unsigned short f2bf(float f) {
    unsigned int x = __float_as_uint(f);
    x += 0x7fffu + ((x >> 16) & 1u);            // round-to-nearest-even
    return (unsigned short)(x >> 16);
}
__device__ __forceinline__ float bf2f(unsigned short h) {
    return __uint_as_float((unsigned int)h << 16);
}

// ---------------------------------------------------------------------------
// Phase 1: counting-sort bucketing with coalesced per-wave run write-out.
// ---------------------------------------------------------------------------
__global__ __launch_bounds__(P1T, 4) void k_bucket(
    const int* __restrict__ src, const int* __restrict__ dst,
    unsigned int* __restrict__ file, int* __restrict__ ctr,
    int E, int nbucket, int cap)
{
    __shared__ unsigned int sorted[CHUNK];   // 64 KB
    __shared__ int cnt[MAXB];
    __shared__ int pre[MAXB + 1];
    __shared__ int gb[MAXB];
    __shared__ int rk[MAXB];

    const int t  = threadIdx.x;
    const int e0 = blockIdx.x * CHUNK;
    const int nE = min(CHUNK, E - e0);

    for (int b = t; b < MAXB; b += P1T) { cnt[b] = 0; rk[b] = 0; }
    __syncthreads();

    const bool full = (nE == CHUNK);
    int4 dc[8];   // register-cached dst values (full blocks only)

    // ---- pass 1: bucket histogram ----
    if (full) {
        const int4* d4 = (const int4*)(dst + e0);
#pragma unroll
        for (int k = 0; k < 8; ++k) dc[k] = d4[t + k * P1T];
#pragma unroll
        for (int k = 0; k < 8; ++k) {
            atomicAdd(&cnt[((unsigned)dc[k].x) >> NPB_SHIFT], 1);
            atomicAdd(&cnt[((unsigned)dc[k].y) >> NPB_SHIFT], 1);
            atomicAdd(&cnt[((unsigned)dc[k].z) >> NPB_SHIFT], 1);
            atomicAdd(&cnt[((unsigned)dc[k].w) >> NPB_SHIFT], 1);
        }
    } else {
        for (int i = t; i < nE; i += P1T)
            atomicAdd(&cnt[((unsigned)dst[e0 + i]) >> NPB_SHIFT], 1);
    }
    __syncthreads();

    // ---- inclusive Hillis-Steele scan: pre[0]=0, pre[b+1]=sum cnt[0..b] ----
    int v = (t < nbucket) ? cnt[t] : 0;
    pre[t + 1] = v;
    if (t == 0) pre[0] = 0;
    __syncthreads();
    for (int off = 1; off < P1T; off <<= 1) {
        int add = (t >= off) ? pre[t + 1 - off] : 0;
        __syncthreads();
        pre[t + 1] += add;
        __syncthreads();
    }

    // ---- reserve global space per (block,bucket) ----
    for (int b = t; b < nbucket; b += P1T) {
        int c = cnt[b];
        gb[b] = c ? atomicAdd(&ctr[b], c) : 0;
    }
    __syncthreads();

    // ---- pass 2: scatter into LDS in bucket order ----
    if (full) {
        const int4* s4 = (const int4*)(src + e0);
#pragma unroll
        for (int k = 0; k < 8; ++k) {
            int4 s = s4[t + k * P1T];
            int4 d = dc[k];
            {
                int b = ((unsigned)d.x) >> NPB_SHIFT;
                int r = atomicAdd(&rk[b], 1);
                sorted[pre[b] + r] = (((unsigned)s.x) << NPB_SHIFT) | ((unsigned)d.x & NPB_MASK);
            }
            {
                int b = ((unsigned)d.y) >> NPB_SHIFT;
                int r = atomicAdd(&rk[b], 1);
                sorted[pre[b] + r] = (((unsigned)s.y) << NPB_SHIFT) | ((unsigned)d.y & NPB_MASK);
            }
            {
                int b = ((unsigned)d.z) >> NPB_SHIFT;
                int r = atomicAdd(&rk[b], 1);
                sorted[pre[b] + r] = (((unsigned)s.z) << NPB_SHIFT) | ((unsigned)d.z & NPB_MASK);
            }
            {
                int b = ((unsigned)d.w) >> NPB_SHIFT;
                int r = atomicAdd(&rk[b], 1);
                sorted[pre[b] + r] = (((unsigned)s.w) << NPB_SHIFT) | ((unsigned)d.w & NPB_MASK);
            }
        }
    } else {
        for (int i = t; i < nE; i += P1T) {
            int d = dst[e0 + i];
            int b = ((unsigned)d) >> NPB_SHIFT;
            unsigned int w = (((unsigned)src[e0 + i]) << NPB_SHIFT) |
                             ((unsigned)d & NPB_MASK);
            int r = atomicAdd(&rk[b], 1);
            sorted[pre[b] + r] = w;
        }
    }
    __syncthreads();

    // ---- pass 3: per-wave run write-out. Wave w handles buckets w, w+8,...
    //      No search: read pre[b]/pre[b+1] once, stream the run coalesced. ----
    {
        const int wid  = t >> 6;
        const int lane = t & 63;
        const int nw   = P1T >> 6;
        for (int b = wid; b < nbucket; b += nw) {
            int s0 = pre[b], s1 = pre[b + 1];
            unsigned int* dp = file + (size_t)b * cap + gb[b];
            for (int j = s0 + lane; j < s1; j += 64)
                __builtin_nontemporal_store(sorted[j], &dp[j - s0]);
        }
    }
}

// ---------------------------------------------------------------------------
// Phase 2a: per-bucket degree histogram -> dinv (f32), u (bf16).
// ---------------------------------------------------------------------------
__global__ __launch_bounds__(P2_THREADS, 8) void k_deg_node1(
    const unsigned int* __restrict__ file, const int* __restrict__ ctr,
    const float* __restrict__ x, float* __restrict__ dinv,
    unsigned short* __restrict__ u, int N, int cap)
{
    __shared__ int cnt[NPB];
    const int b = blockIdx.x;
    cnt[threadIdx.x] = 0;
    __syncthreads();
    const int n = ctr[b];
    const unsigned int* f = file + (size_t)b * cap;
    const int T4 = P2_THREADS * 4;
    int i = threadIdx.x * 4;
    for (; i + T4 + 3 < n; i += 2 * T4) {
        uint4v w0 = NTL4(f + i);
        uint4v w1 = NTL4(f + i + T4);
        atomicAdd(&cnt[w0.x & NPB_MASK], 1);
        atomicAdd(&cnt[w0.y & NPB_MASK], 1);
        atomicAdd(&cnt[w0.z & NPB_MASK], 1);
        atomicAdd(&cnt[w0.w & NPB_MASK], 1);
        atomicAdd(&cnt[w1.x & NPB_MASK], 1);
        atomicAdd(&cnt[w1.y & NPB_MASK], 1);
        atomicAdd(&cnt[w1.z & NPB_MASK], 1);
        atomicAdd(&cnt[w1.w & NPB_MASK], 1);
    }
    for (; i + 3 < n; i += T4) {
        uint4v w = NTL4(f + i);
        atomicAdd(&cnt[w.x & NPB_MASK], 1);
        atomicAdd(&cnt[w.y & NPB_MASK], 1);
        atomicAdd(&cnt[w.z & NPB_MASK], 1);
        atomicAdd(&cnt[w.w & NPB_MASK], 1);
    }
    for (int j = (n & ~3) + threadIdx.x; j < n; j += P2_THREADS)
        atomicAdd(&cnt[__builtin_nontemporal_load(f + j) & NPB_MASK], 1);
    __syncthreads();
    const int g = b * NPB + threadIdx.x;
    if (g < N) {
        float dv = rsqrtf((float)(cnt[threadIdx.x] + 1));  // +1 self-loop
        dinv[g] = dv;
        u[g] = f2bf(x[g] * dv);
    }
}

// ---------------------------------------------------------------------------
// Phase 2b: agg1 = sum u[src] (LDS) -> s1 -> MLP 1->16->2 -> q (2xbf16).
// ---------------------------------------------------------------------------
__global__ __launch_bounds__(P2_THREADS, 8) void k_agg1_mlp(
    const unsigned int* __restrict__ file, const int* __restrict__ ctr,
    const unsigned short* __restrict__ u, const float* __restrict__ dinv,
    const float* __restrict__ W1, const float* __restrict__ b1,
    const float* __restrict__ W2, unsigned int* __restrict__ q, int N, int cap)
{
    __shared__ float acc[NPB];
    const int b = blockIdx.x;
    acc[threadIdx.x] = 0.f;
    __syncthreads();
    const int n = ctr[b];
    const unsigned int* f = file + (size_t)b * cap;
    const int T4 = P2_THREADS * 4;
    int i = threadIdx.x * 4;
    for (; i + T4 + 3 < n; i += 2 * T4) {
        uint4v w0 = NTL4(f + i);
        uint4v w1 = NTL4(f + i + T4);
        float v0 = bf2f(u[w0.x >> NPB_SHIFT]);
        float v1 = bf2f(u[w0.y >> NPB_SHIFT]);
        float v2 = bf2f(u[w0.z >> NPB_SHIFT]);
        float v3 = bf2f(u[w0.w >> NPB_SHIFT]);
        float v4 = bf2f(u[w1.x >> NPB_SHIFT]);
        float v5 = bf2f(u[w1.y >> NPB_SHIFT]);
        float v6 = bf2f(u[w1.z >> NPB_SHIFT]);
        float v7 = bf2f(u[w1.w >> NPB_SHIFT]);
        atomicAdd(&acc[w0.x & NPB_MASK], v0);
        atomicAdd(&acc[w0.y & NPB_MASK], v1);
        atomicAdd(&acc[w0.z & NPB_MASK], v2);
        atomicAdd(&acc[w0.w & NPB_MASK], v3);
        atomicAdd(&acc[w1.x & NPB_MASK], v4);
        atomicAdd(&acc[w1.y & NPB_MASK], v5);
        atomicAdd(&acc[w1.z & NPB_MASK], v6);
        atomicAdd(&acc[w1.w & NPB_MASK], v7);
    }
    for (; i + 3 < n; i += T4) {
        uint4v w = NTL4(f + i);
        float v0 = bf2f(u[w.x >> NPB_SHIFT]);
        float v1 = bf2f(u[w.y >> NPB_SHIFT]);
        float v2 = bf2f(u[w.z >> NPB_SHIFT]);
        float v3 = bf2f(u[w.w >> NPB_SHIFT]);
        atomicAdd(&acc[w.x & NPB_MASK], v0);
        atomicAdd(&acc[w.y & NPB_MASK], v1);
        atomicAdd(&acc[w.z & NPB_MASK], v2);
        atomicAdd(&acc[w.w & NPB_MASK], v3);
    }
    for (int j = (n & ~3) + threadIdx.x; j < n; j += P2_THREADS) {
        unsigned int w = __builtin_nontemporal_load(f + j);
        atomicAdd(&acc[w & NPB_MASK], bf2f(u[w >> NPB_SHIFT]));
    }
    __syncthreads();
    const int g = b * NPB + threadIdx.x;
    if (g < N) {
        float dv = dinv[g];
        float s1 = (acc[threadIdx.x] + bf2f(u[g])) * dv;
        float c0 = 0.f, c1 = 0.f;
#pragma unroll
        for (int k = 0; k < 16; ++k) {
            float h = fmaxf(fmaf(s1, W1[k], b1[k]), 0.f);
            c0 = fmaf(h, W2[2 * k], c0);
            c1 = fmaf(h, W2[2 * k + 1], c1);
        }
        q[g] = (unsigned int)f2bf(c0 * dv) |
               ((unsigned int)f2bf(c1 * dv) << 16);
    }
}

// ---------------------------------------------------------------------------
// Phase 2c: agg2 = sum unpack(q[src]) (LDS x2) -> +self, *dinv, +b2, lsm.
// ---------------------------------------------------------------------------
__global__ __launch_bounds__(P2_THREADS, 8) void k_agg2_out(
    const unsigned int* __restrict__ file, const int* __restrict__ ctr,
    const unsigned int* __restrict__ q, const float* __restrict__ dinv,
    const float* __restrict__ b2, float2* __restrict__ out, int N, int cap)
{
    __shared__ float a0[NPB];
    __shared__ float a1[NPB];
    const int b = blockIdx.x;
    a0[threadIdx.x] = 0.f;
    a1[threadIdx.x] = 0.f;
    __syncthreads();
    const int n = ctr[b];
    const unsigned int* f = file + (size_t)b * cap;
    const int T4 = P2_THREADS * 4;
    int i = threadIdx.x * 4;
    for (; i + T4 + 3 < n; i += 2 * T4) {
        uint4v w0 = NTL4(f + i);
        uint4v w1 = NTL4(f + i + T4);
        unsigned int g0 = q[w0.x >> NPB_SHIFT];
        unsigned int g1 = q[w0.y >> NPB_SHIFT];
        unsigned int g2 = q[w0.z >> NPB_SHIFT];
        unsigned int g3 = q[w0.w >> NPB_SHIFT];
        unsigned int g4 = q[w1.x >> NPB_SHIFT];
        unsigned int g5 = q[w1.y >> NPB_SHIFT];
        unsigned int g6 = q[w1.z >> NPB_SHIFT];
        unsigned int g7 = q[w1.w >> NPB_SHIFT];
        atomicAdd(&a0[w0.x & NPB_MASK], bf2f((unsigned short)g0));
        atomicAdd(&a1[w0.x & NPB_MASK], bf2f((unsigned short)(g0 >> 16)));
        atomicAdd(&a0[w0.y & NPB_MASK], bf2f((unsigned short)g1));
        atomicAdd(&a1[w0.y & NPB_MASK], bf2f((unsigned short)(g1 >> 16)));
        atomicAdd(&a0[w0.z & NPB_MASK], bf2f((unsigned short)g2));
        atomicAdd(&a1[w0.z & NPB_MASK], bf2f((unsigned short)(g2 >> 16)));
        atomicAdd(&a0[w0.w & NPB_MASK], bf2f((unsigned short)g3));
        atomicAdd(&a1[w0.w & NPB_MASK], bf2f((unsigned short)(g3 >> 16)));
        atomicAdd(&a0[w1.x & NPB_MASK], bf2f((unsigned short)g4));
        atomicAdd(&a1[w1.x & NPB_MASK], bf2f((unsigned short)(g4 >> 16)));
        atomicAdd(&a0[w1.y & NPB_MASK], bf2f((unsigned short)g5));
        atomicAdd(&a1[w1.y & NPB_MASK], bf2f((unsigned short)(g5 >> 16)));
        atomicAdd(&a0[w1.z & NPB_MASK], bf2f((unsigned short)g6));
        atomicAdd(&a1[w1.z & NPB_MASK], bf2f((unsigned short)(g6 >> 16)));
        atomicAdd(&a0[w1.w & NPB_MASK], bf2f((unsigned short)g7));
        atomicAdd(&a1[w1.w & NPB_MASK], bf2f((unsigned short)(g7 >> 16)));
    }
    for (; i + 3 < n; i += T4) {
        uint4v w = NTL4(f + i);
        unsigned int g0 = q[w.x >> NPB_SHIFT];
        unsigned int g1 = q[w.y >> NPB_SHIFT];
        unsigned int g2 = q[w.z >> NPB_SHIFT];
        unsigned int g3 = q[w.w >> NPB_SHIFT];
        atomicAdd(&a0[w.x & NPB_MASK], bf2f((unsigned short)g0));
        atomicAdd(&a1[w.x & NPB_MASK], bf2f((unsigned short)(g0 >> 16)));
        atomicAdd(&a0[w.y & NPB_MASK], bf2f((unsigned short)g1));
        atomicAdd(&a1[w.y & NPB_MASK], bf2f((unsigned short)(g1 >> 16)));
        atomicAdd(&a0[w.z & NPB_MASK], bf2f((unsigned short)g2));
        atomicAdd(&a1[w.z & NPB_MASK], bf2f((unsigned short)(g2 >> 16)));
        atomicAdd(&a0[w.w & NPB_MASK], bf2f((unsigned short)g3));
        atomicAdd(&a1[w.w & NPB_MASK], bf2f((unsigned short)(g3 >> 16)));
    }
    for (int j = (n & ~3) + threadIdx.x; j < n; j += P2_THREADS) {
        unsigned int w = __builtin_nontemporal_load(f + j);
        unsigned int gq = q[w >> NPB_SHIFT];
        atomicAdd(&a0[w & NPB_MASK], bf2f((unsigned short)gq));
        atomicAdd(&a1[w & NPB_MASK], bf2f((unsigned short)(gq >> 16)));
    }
    __syncthreads();
    const int g = b * NPB + threadIdx.x;
    if (g < N) {
        float dv = dinv[g];
        unsigned int qi = q[g];
        float o0 = (a0[threadIdx.x] + bf2f((unsigned short)qi)) * dv + b2[0];
        float o1 = (a1[threadIdx.x] + bf2f((unsigned short)(qi >> 16))) * dv + b2[1];
        float m = fmaxf(o0, o1);
        float l = m + logf(expf(o0 - m) + expf(o1 - m));
        out[g] = make_float2(o0 - l, o1 - l);
    }
}

// ===========================================================================
// Fallback path (direct-atomic, fp32) if workspace is too small.
// ===========================================================================
#define NT 256
__global__ __launch_bounds__(NT) void fb_deg(const int* __restrict__ dst,
                                             int* __restrict__ deg, int E) {
    int e = blockIdx.x * blockDim.x + threadIdx.x;
    if (e < E) atomicAdd(&deg[dst[e]], 1);
}
__global__ __launch_bounds__(NT) void fb_node1(const float* __restrict__ x,
                                               const int* __restrict__ deg,
                                               float* __restrict__ dinv,
                                               float* __restrict__ u, int N) {
    int i = blockIdx.x * blockDim.x + threadIdx.x;
    if (i < N) {
        float dv = rsqrtf((float)(deg[i] + 1));
        dinv[i] = dv;
        u[i] = x[i] * dv;
    }
}
__global__ __launch_bounds__(NT) void fb_edge1(const int* __restrict__ src,
                                               const int* __restrict__ dst,
                                               const float* __restrict__ u,
                                               float* __restrict__ agg1, int E) {
    int e = blockIdx.x * blockDim.x + threadIdx.x;
    if (e < E) atomicAdd(&agg1[dst[e]], u[src[e]]);
}
__global__ __launch_bounds__(NT) void fb_node2(const float* __restrict__ agg1,
                                               const float* __restrict__ u,
                                               const float* __restrict__ dinv,
                                               const float* __restrict__ W1,
                                               const float* __restrict__ b1,
                                               const float* __restrict__ W2,
                                               float2* __restrict__ q, int N) {
    int i = blockIdx.x * blockDim.x + threadIdx.x;
    if (i < N) {
        float dv = dinv[i];
        float s1 = (agg1[i] + u[i]) * dv;
        float c0 = 0.f, c1 = 0.f;
#pragma unroll
        for (int k = 0; k < 16; ++k) {
            float h = fmaxf(fmaf(s1, W1[k], b1[k]), 0.f);
            c0 = fmaf(h, W2[2 * k], c0);
            c1 = fmaf(h, W2[2 * k + 1], c1);
        }
        q[i] = make_float2(c0 * dv, c1 * dv);
    }
}
__global__ __launch_bounds__(NT) void fb_edge2(const int* __restrict__ src,
                                               const int* __restrict__ dst,
                                               const float2* __restrict__ q,
                                               float* __restrict__ agg2, int E) {
    int e = blockIdx.x * blockDim.x + threadIdx.x;
    if (e < E) {
        float2 qq = q[src[e]];
        atomicAdd(&agg2[2 * dst[e]], qq.x);
        atomicAdd(&agg2[2 * dst[e] + 1], qq.y);
    }
}
__global__ __launch_bounds__(NT) void fb_node3(const float* __restrict__ agg2,
                                               const float2* __restrict__ q,
                                               const float* __restrict__ dinv,
                                               const float* __restrict__ b2,
                                               float2* __restrict__ out, int N) {
    int i = blockIdx.x * blockDim.x + threadIdx.x;
    if (i < N) {
        float dv = dinv[i];
        float2 qi = q[i];
        float o0 = (agg2[2 * i] + qi.x) * dv + b2[0];
        float o1 = (agg2[2 * i + 1] + qi.y) * dv + b2[1];
        float m = fmaxf(o0, o1);
        float l = m + logf(expf(o0 - m) + expf(o1 - m));
        out[i] = make_float2(o0 - l, o1 - l);
    }
}

// ===========================================================================
extern "C" void kernel_launch(void* const* d_in, const int* in_sizes, int n_in,
                              void* d_out, int out_size, void* d_ws, size_t ws_size,
                              hipStream_t stream) {
    const float* x  = (const float*)d_in[0];
    const int* ei   = (const int*)d_in[1];
    const float* W1 = (const float*)d_in[2];
    const float* b1 = (const float*)d_in[3];
    const float* W2 = (const float*)d_in[4];
    const float* b2 = (const float*)d_in[5];

    const int N = in_sizes[0];
    const int E = in_sizes[1] / 2;
    const int* src = ei;
    const int* dst = ei + E;

    const int nbucket = (N + NPB - 1) / NPB;
    // capacity: mean + slack (uniform dsts: sd ~ sqrt(mean)); 64-aligned so
    // every bucket base stays 16B-aligned for uint4v loads.
    const int cap = ((E / nbucket + 4096) + 63) & ~63;

    auto align_up = [](size_t v) { return (v + 255) & ~(size_t)255; };
    size_t off_ctr  = 0;
    size_t off_file = align_up((size_t)MAXB * sizeof(int));
    size_t off_dinv = align_up(off_file + (size_t)nbucket * cap * sizeof(unsigned int));
    size_t off_u    = align_up(off_dinv + (size_t)N * sizeof(float));
    size_t off_q    = align_up(off_u + (size_t)N * sizeof(unsigned short));
    size_t needed   = off_q + (size_t)N * sizeof(unsigned int);

    char* ws = (char*)d_ws;

    if (nbucket <= MAXB && needed <= ws_size) {
        int*            ctr  = (int*)(ws + off_ctr);
        unsigned int*   file = (unsigned int*)(ws + off_file);
        float*          dinv = (float*)(ws + off_dinv);
        unsigned short* u    = (unsigned short*)(ws + off_u);
        unsigned int*   q    = (unsigned int*)(ws + off_q);

        (void)hipMemsetAsync(ctr, 0, (size_t)MAXB * sizeof(int), stream);

        const int p1Blocks = (E + CHUNK - 1) / CHUNK;
        k_bucket   <<<p1Blocks, P1T, 0, stream>>>(src, dst, file, ctr, E, nbucket, cap);
        k_deg_node1<<<nbucket, P2_THREADS, 0, stream>>>(file, ctr, x, dinv, u, N, cap);
        k_agg1_mlp <<<nbucket, P2_THREADS, 0, stream>>>(file, ctr, u, dinv, W1, b1, W2, q, N, cap);
        k_agg2_out <<<nbucket, P2_THREADS, 0, stream>>>(file, ctr, q, dinv, b2, (float2*)d_out, N, cap);
    } else {
        int*    deg  = (int*)   (ws);
        float*  agg1 = (float*) (ws + (size_t)4 * N);
        float*  agg2 = (float*) (ws + (size_t)8 * N);
        float*  dinv = (float*) (ws + (size_t)16 * N);
        float*  u    = (float*) (ws + (size_t)20 * N);
        float2* q    = (float2*)(ws + (size_t)24 * N);
        (void)hipMemsetAsync(ws, 0, (size_t)16 * N, stream);
        const int nodeBlocks = (N + NT - 1) / NT;
        const int edgeBlocks = (E + NT - 1) / NT;
        fb_deg  <<<edgeBlocks, NT, 0, stream>>>(dst, deg, E);
        fb_node1<<<nodeBlocks, NT, 0, stream>>>(x, deg, dinv, u, N);
        fb_edge1<<<edgeBlocks, NT, 0, stream>>>(src, dst, u, agg1, E);
        fb_node2<<<nodeBlocks, NT, 0, stream>>>(agg1, u, dinv, W1, b1, W2, q, N);
        fb_edge2<<<edgeBlocks, NT, 0, stream>>>(src, dst, q, agg2, E);
        fb_node3<<<nodeBlocks, NT, 0, stream>>>(agg2, q, dinv, b2, (float2*)d_out, N);
    }
}

// Round 7
// 237.846 us; speedup vs baseline: 6.6110x; 1.1763x over previous
//
#include <hip/hip_runtime.h>
#include <math.h>

// ---------------------------------------------------------------------------
// Pipeline v3 — full two-level dst sort, atomic-free aggregation.
// Round-6 diagnosis: duration tracks LDS atomics/edge (~4cyc per lane-atomic,
// serialized DS RMW), invariant to ILP and gather footprint. So:
//   k_bucket : radix pass 1 (dst>>10) — LDS counting sort per 16k chunk,
//              coalesced run write-out. (2 LDS atomics/edge, unchanged)
//   k_sort   : radix pass 2 (dst&1023) per bucket — rank atomic doubles as
//              degree histogram (1 LDS atomic/edge), entries reg-cached,
//              LDS scatter, in-place coalesced write-back of sorted src,
//              CSR start[] out; fused node1 epilogue (dinv, u=bf16(x*dinv)).
//   k_agg1   : NO atomics. thread=node walks its CSR segment, gathers u,
//              MLP 1->16->2, q packed 2xbf16.
//   k_agg2   : NO atomics. same walk on q, +self, *dinv, +b2, log_softmax.
// ---------------------------------------------------------------------------

typedef unsigned int uint4v __attribute__((ext_vector_type(4)));

#define NPB 1024            // nodes per bucket
#define NPB_SHIFT 10
#define NPB_MASK (NPB - 1)
#define MAXB 512            // max buckets
#define P1T 512             // k_bucket threads
#define CHUNK 16384         // edges per k_bucket block
#define SORT_CAP 17408      // per-bucket file capacity (mean 16360 + 8sigma)
#define SPT 17              // SORT_CAP / 1024 entries per k_sort thread

__device__ __forceinline__ unsigned short f2bf(float f) {
    unsigned int x = __float_as_uint(f);
    x += 0x7fffu + ((x >> 16) & 1u);            // round-to-nearest-even
    return (unsigned short)(x >> 16);
}
__device__ __forceinline__ float bf2f(unsigned short h) {
    return __uint_as_float((unsigned int)h << 16);
}

// ---------------------------------------------------------------------------
// Phase 1: bucket by dst>>10, coalesced per-wave run write-out.
// ---------------------------------------------------------------------------
__global__ __launch_bounds__(P1T, 4) void k_bucket(
    const int* __restrict__ src, const int* __restrict__ dst,
    unsigned int* __restrict__ file, int* __restrict__ ctr,
    int E, int nbucket, int cap)
{
    __shared__ unsigned int sorted[CHUNK];   // 64 KB
    __shared__ int cnt[MAXB];
    __shared__ int pre[MAXB + 1];
    __shared__ int gb[MAXB];
    __shared__ int rk[MAXB];

    const int t  = threadIdx.x;
    const int e0 = blockIdx.x * CHUNK;
    const int nE = min(CHUNK, E - e0);

    for (int b = t; b < MAXB; b += P1T) { cnt[b] = 0; rk[b] = 0; }
    __syncthreads();

    const bool full = (nE == CHUNK);
    int4 dc[8];

    if (full) {
        const int4* d4 = (const int4*)(dst + e0);
#pragma unroll
        for (int k = 0; k < 8; ++k) dc[k] = d4[t + k * P1T];
#pragma unroll
        for (int k = 0; k < 8; ++k) {
            atomicAdd(&cnt[((unsigned)dc[k].x) >> NPB_SHIFT], 1);
            atomicAdd(&cnt[((unsigned)dc[k].y) >> NPB_SHIFT], 1);
            atomicAdd(&cnt[((unsigned)dc[k].z) >> NPB_SHIFT], 1);
            atomicAdd(&cnt[((unsigned)dc[k].w) >> NPB_SHIFT], 1);
        }
    } else {
        for (int i = t; i < nE; i += P1T)
            atomicAdd(&cnt[((unsigned)dst[e0 + i]) >> NPB_SHIFT], 1);
    }
    __syncthreads();

    int v = (t < nbucket) ? cnt[t] : 0;
    pre[t + 1] = v;
    if (t == 0) pre[0] = 0;
    __syncthreads();
    for (int off = 1; off < P1T; off <<= 1) {
        int add = (t >= off) ? pre[t + 1 - off] : 0;
        __syncthreads();
        pre[t + 1] += add;
        __syncthreads();
    }

    for (int b = t; b < nbucket; b += P1T) {
        int c = cnt[b];
        gb[b] = c ? atomicAdd(&ctr[b], c) : 0;
    }
    __syncthreads();

    if (full) {
        const int4* s4 = (const int4*)(src + e0);
#pragma unroll
        for (int k = 0; k < 8; ++k) {
            int4 s = s4[t + k * P1T];
            int4 d = dc[k];
            {
                int b = ((unsigned)d.x) >> NPB_SHIFT;
                int r = atomicAdd(&rk[b], 1);
                sorted[pre[b] + r] = (((unsigned)s.x) << NPB_SHIFT) | ((unsigned)d.x & NPB_MASK);
            }
            {
                int b = ((unsigned)d.y) >> NPB_SHIFT;
                int r = atomicAdd(&rk[b], 1);
                sorted[pre[b] + r] = (((unsigned)s.y) << NPB_SHIFT) | ((unsigned)d.y & NPB_MASK);
            }
            {
                int b = ((unsigned)d.z) >> NPB_SHIFT;
                int r = atomicAdd(&rk[b], 1);
                sorted[pre[b] + r] = (((unsigned)s.z) << NPB_SHIFT) | ((unsigned)d.z & NPB_MASK);
            }
            {
                int b = ((unsigned)d.w) >> NPB_SHIFT;
                int r = atomicAdd(&rk[b], 1);
                sorted[pre[b] + r] = (((unsigned)s.w) << NPB_SHIFT) | ((unsigned)d.w & NPB_MASK);
            }
        }
    } else {
        for (int i = t; i < nE; i += P1T) {
            int d = dst[e0 + i];
            int b = ((unsigned)d) >> NPB_SHIFT;
            unsigned int w = (((unsigned)src[e0 + i]) << NPB_SHIFT) |
                             ((unsigned)d & NPB_MASK);
            int r = atomicAdd(&rk[b], 1);
            sorted[pre[b] + r] = w;
        }
    }
    __syncthreads();

    {   // per-wave run write-out, clamped to cap
        const int wid  = t >> 6;
        const int lane = t & 63;
        const int nw   = P1T >> 6;
        for (int b = wid; b < nbucket; b += nw) {
            int s0 = pre[b], s1 = pre[b + 1];
            int base = gb[b];
            unsigned int* dp = file + (size_t)b * cap;
            for (int j = s0 + lane; j < s1; j += 64) {
                int idx = base + (j - s0);
                if (idx < cap)
                    __builtin_nontemporal_store(sorted[j], &dp[idx]);
            }
        }
    }
}

// ---------------------------------------------------------------------------
// Phase 2: per-bucket sort by dstlo. One LDS atomic/edge (rank == histogram).
// In-place: reads file entries into regs, writes back sorted src values.
// Fused: deg -> dinv (f32), u = bf16(x*dinv); CSR start[] out.
// ---------------------------------------------------------------------------
__global__ __launch_bounds__(NPB) void k_sort(
    unsigned int* __restrict__ file, const int* __restrict__ ctr,
    int* __restrict__ start, const float* __restrict__ x,
    float* __restrict__ dinv, unsigned short* __restrict__ u,
    int N, int cap)
{
    __shared__ unsigned int sorted[SORT_CAP];  // 69.6 KB
    __shared__ int cnt[NPB];
    __shared__ int pre[NPB + 1];

    const int t = threadIdx.x;
    const int b = blockIdx.x;
    const int nb = min(ctr[b], cap);
    unsigned int* f = file + (size_t)b * cap;

    cnt[t] = 0;
    __syncthreads();

    unsigned int ev[SPT];
    int rk_[SPT];
#pragma unroll
    for (int k = 0; k < SPT; ++k) {
        int i = t + (k << NPB_SHIFT);
        if (i < nb) ev[k] = __builtin_nontemporal_load(f + i);
    }
#pragma unroll
    for (int k = 0; k < SPT; ++k) {
        int i = t + (k << NPB_SHIFT);
        if (i < nb) rk_[k] = atomicAdd(&cnt[ev[k] & NPB_MASK], 1);
    }
    __syncthreads();

    // exclusive scan: pre[0]=0, pre[i] = sum cnt[0..i-1]
    pre[t + 1] = cnt[t];
    if (t == 0) pre[0] = 0;
    __syncthreads();
    for (int off = 1; off < NPB; off <<= 1) {
        int add = (t >= off) ? pre[t + 1 - off] : 0;
        __syncthreads();
        pre[t + 1] += add;
        __syncthreads();
    }

    // scatter src into dst-sorted LDS order
#pragma unroll
    for (int k = 0; k < SPT; ++k) {
        int i = t + (k << NPB_SHIFT);
        if (i < nb)
            sorted[pre[ev[k] & NPB_MASK] + rk_[k]] = ev[k] >> NPB_SHIFT;
    }
    __syncthreads();

    // coalesced write-back (in-place over this bucket's file region)
    for (int i = t; i < nb; i += NPB)
        __builtin_nontemporal_store(sorted[i], &f[i]);

    // CSR offsets
    start[b * (NPB + 1) + t] = pre[t];
    if (t == 0) start[b * (NPB + 1) + NPB] = pre[NPB];

    // node epilogue
    const int g = b * NPB + t;
    if (g < N) {
        float dv = rsqrtf((float)(cnt[t] + 1));   // +1 self-loop
        dinv[g] = dv;
        u[g] = f2bf(x[g] * dv);
    }
}

// ---------------------------------------------------------------------------
// Phase 3: atomic-free segment walk. agg1 -> MLP -> q (2xbf16 packed).
// ---------------------------------------------------------------------------
__global__ __launch_bounds__(256) void k_agg1(
    const unsigned int* __restrict__ file, const int* __restrict__ start,
    const unsigned short* __restrict__ u, const float* __restrict__ dinv,
    const float* __restrict__ W1, const float* __restrict__ b1,
    const float* __restrict__ W2, unsigned int* __restrict__ q,
    int N, int cap)
{
    int g = blockIdx.x * 256 + threadIdx.x;
    if (g >= N) return;
    int b = g >> NPB_SHIFT, loc = g & NPB_MASK;
    const int* st = start + b * (NPB + 1);
    int e0 = st[loc], e1 = st[loc + 1];
    const unsigned int* f = file + (size_t)b * cap;

    float acc = 0.f;
    int j = e0;
    for (; j + 4 <= e1; j += 4) {
        unsigned int s0 = f[j], s1 = f[j + 1], s2 = f[j + 2], s3 = f[j + 3];
        float a = bf2f(u[s0]), bb = bf2f(u[s1]);
        float c = bf2f(u[s2]), d = bf2f(u[s3]);
        acc += (a + bb) + (c + d);
    }
    for (; j < e1; ++j) acc += bf2f(u[f[j]]);

    float dv = dinv[g];
    float s1v = (acc + bf2f(u[g])) * dv;
    float c0 = 0.f, c1 = 0.f;
#pragma unroll
    for (int k = 0; k < 16; ++k) {
        float h = fmaxf(fmaf(s1v, W1[k], b1[k]), 0.f);
        c0 = fmaf(h, W2[2 * k], c0);
        c1 = fmaf(h, W2[2 * k + 1], c1);
    }
    q[g] = (unsigned int)f2bf(c0 * dv) | ((unsigned int)f2bf(c1 * dv) << 16);
}

// ---------------------------------------------------------------------------
// Phase 4: atomic-free walk on q -> +self, *dinv, +b2, log_softmax.
// ---------------------------------------------------------------------------
__global__ __launch_bounds__(256) void k_agg2(
    const unsigned int* __restrict__ file, const int* __restrict__ start,
    const unsigned int* __restrict__ q, const float* __restrict__ dinv,
    const float* __restrict__ b2, float2* __restrict__ out,
    int N, int cap)
{
    int g = blockIdx.x * 256 + threadIdx.x;
    if (g >= N) return;
    int b = g >> NPB_SHIFT, loc = g & NPB_MASK;
    const int* st = start + b * (NPB + 1);
    int e0 = st[loc], e1 = st[loc + 1];
    const unsigned int* f = file + (size_t)b * cap;

    float a0 = 0.f, a1 = 0.f;
    int j = e0;
    for (; j + 4 <= e1; j += 4) {
        unsigned int g0 = q[f[j]], g1 = q[f[j + 1]];
        unsigned int g2 = q[f[j + 2]], g3 = q[f[j + 3]];
        a0 += (bf2f((unsigned short)g0) + bf2f((unsigned short)g1)) +
              (bf2f((unsigned short)g2) + bf2f((unsigned short)g3));
        a1 += (bf2f((unsigned short)(g0 >> 16)) + bf2f((unsigned short)(g1 >> 16))) +
              (bf2f((unsigned short)(g2 >> 16)) + bf2f((unsigned short)(g3 >> 16)));
    }
    for (; j < e1; ++j) {
        unsigned int gq = q[f[j]];
        a0 += bf2f((unsigned short)gq);
        a1 += bf2f((unsigned short)(gq >> 16));
    }

    float dv = dinv[g];
    unsigned int qi = q[g];
    float o0 = (a0 + bf2f((unsigned short)qi)) * dv + b2[0];
    float o1 = (a1 + bf2f((unsigned short)(qi >> 16))) * dv + b2[1];
    float m = fmaxf(o0, o1);
    float l = m + logf(expf(o0 - m) + expf(o1 - m));
    out[g] = make_float2(o0 - l, o1 - l);
}

// ===========================================================================
// Fallback path (direct-atomic, fp32) if workspace/shape doesn't fit.
// ===========================================================================
#define NT 256
__global__ __launch_bounds__(NT) void fb_deg(const int* __restrict__ dst,
                                             int* __restrict__ deg, int E) {
    int e = blockIdx.x * blockDim.x + threadIdx.x;
    if (e < E) atomicAdd(&deg[dst[e]], 1);
}
__global__ __launch_bounds__(NT) void fb_node1(const float* __restrict__ x,
                                               const int* __restrict__ deg,
                                               float* __restrict__ dinv,
                                               float* __restrict__ u, int N) {
    int i = blockIdx.x * blockDim.x + threadIdx.x;
    if (i < N) {
        float dv = rsqrtf((float)(deg[i] + 1));
        dinv[i] = dv;
        u[i] = x[i] * dv;
    }
}
__global__ __launch_bounds__(NT) void fb_edge1(const int* __restrict__ src,
                                               const int* __restrict__ dst,
                                               const float* __restrict__ u,
                                               float* __restrict__ agg1, int E) {
    int e = blockIdx.x * blockDim.x + threadIdx.x;
    if (e < E) atomicAdd(&agg1[dst[e]], u[src[e]]);
}
__global__ __launch_bounds__(NT) void fb_node2(const float* __restrict__ agg1,
                                               const float* __restrict__ u,
                                               const float* __restrict__ dinv,
                                               const float* __restrict__ W1,
                                               const float* __restrict__ b1,
                                               const float* __restrict__ W2,
                                               float2* __restrict__ q, int N) {
    int i = blockIdx.x * blockDim.x + threadIdx.x;
    if (i < N) {
        float dv = dinv[i];
        float s1 = (agg1[i] + u[i]) * dv;
        float c0 = 0.f, c1 = 0.f;
#pragma unroll
        for (int k = 0; k < 16; ++k) {
            float h = fmaxf(fmaf(s1, W1[k], b1[k]), 0.f);
            c0 = fmaf(h, W2[2 * k], c0);
            c1 = fmaf(h, W2[2 * k + 1], c1);
        }
        q[i] = make_float2(c0 * dv, c1 * dv);
    }
}
__global__ __launch_bounds__(NT) void fb_edge2(const int* __restrict__ src,
                                               const int* __restrict__ dst,
                                               const float2* __restrict__ q,
                                               float* __restrict__ agg2, int E) {
    int e = blockIdx.x * blockDim.x + threadIdx.x;
    if (e < E) {
        float2 qq = q[src[e]];
        atomicAdd(&agg2[2 * dst[e]], qq.x);
        atomicAdd(&agg2[2 * dst[e] + 1], qq.y);
    }
}
__global__ __launch_bounds__(NT) void fb_node3(const float* __restrict__ agg2,
                                               const float2* __restrict__ q,
                                               const float* __restrict__ dinv,
                                               const float* __restrict__ b2,
                                               float2* __restrict__ out, int N) {
    int i = blockIdx.x * blockDim.x + threadIdx.x;
    if (i < N) {
        float dv = dinv[i];
        float2 qi = q[i];
        float o0 = (agg2[2 * i] + qi.x) * dv + b2[0];
        float o1 = (agg2[2 * i + 1] + qi.y) * dv + b2[1];
        float m = fmaxf(o0, o1);
        float l = m + logf(expf(o0 - m) + expf(o1 - m));
        out[i] = make_float2(o0 - l, o1 - l);
    }
}

// ===========================================================================
extern "C" void kernel_launch(void* const* d_in, const int* in_sizes, int n_in,
                              void* d_out, int out_size, void* d_ws, size_t ws_size,
                              hipStream_t stream) {
    const float* x  = (const float*)d_in[0];
    const int* ei   = (const int*)d_in[1];
    const float* W1 = (const float*)d_in[2];
    const float* b1 = (const float*)d_in[3];
    const float* W2 = (const float*)d_in[4];
    const float* b2 = (const float*)d_in[5];

    const int N = in_sizes[0];
    const int E = in_sizes[1] / 2;
    const int* src = ei;
    const int* dst = ei + E;

    const int nbucket = (N + NPB - 1) / NPB;
    const int cap = ((E / nbucket + 1024) + 63) & ~63;   // must be <= SORT_CAP

    auto align_up = [](size_t v) { return (v + 255) & ~(size_t)255; };
    size_t off_ctr   = 0;
    size_t off_file  = align_up((size_t)MAXB * sizeof(int));
    size_t off_start = align_up(off_file + (size_t)nbucket * SORT_CAP * sizeof(unsigned int));
    size_t off_dinv  = align_up(off_start + (size_t)nbucket * (NPB + 1) * sizeof(int));
    size_t off_u     = align_up(off_dinv + (size_t)N * sizeof(float));
    size_t off_q     = align_up(off_u + (size_t)N * sizeof(unsigned short));
    size_t needed    = off_q + (size_t)N * sizeof(unsigned int);

    char* ws = (char*)d_ws;

    if (nbucket <= MAXB && cap <= SORT_CAP && needed <= ws_size) {
        int*            ctr   = (int*)(ws + off_ctr);
        unsigned int*   file  = (unsigned int*)(ws + off_file);
        int*            start = (int*)(ws + off_start);
        float*          dinv  = (float*)(ws + off_dinv);
        unsigned short* u     = (unsigned short*)(ws + off_u);
        unsigned int*   q     = (unsigned int*)(ws + off_q);

        (void)hipMemsetAsync(ctr, 0, (size_t)MAXB * sizeof(int), stream);

        const int p1Blocks  = (E + CHUNK - 1) / CHUNK;
        const int nodBlocks = (N + 255) / 256;
        k_bucket<<<p1Blocks, P1T, 0, stream>>>(src, dst, file, ctr, E, nbucket, SORT_CAP);
        k_sort  <<<nbucket, NPB, 0, stream>>>(file, ctr, start, x, dinv, u, N, SORT_CAP);
        k_agg1  <<<nodBlocks, 256, 0, stream>>>(file, start, u, dinv, W1, b1, W2, q, N, SORT_CAP);
        k_agg2  <<<nodBlocks, 256, 0, stream>>>(file, start, q, dinv, b2, (float2*)d_out, N, SORT_CAP);
    } else {
        int*    deg  = (int*)   (ws);
        float*  agg1 = (float*) (ws + (size_t)4 * N);
        float*  agg2 = (float*) (ws + (size_t)8 * N);
        float*  dinv = (float*) (ws + (size_t)16 * N);
        float*  u    = (float*) (ws + (size_t)20 * N);
        float2* q    = (float2*)(ws + (size_t)24 * N);
        (void)hipMemsetAsync(ws, 0, (size_t)16 * N, stream);
        const int nodeBlocks = (N + NT - 1) / NT;
        const int edgeBlocks = (E + NT - 1) / NT;
        fb_deg  <<<edgeBlocks, NT, 0, stream>>>(dst, deg, E);
        fb_node1<<<nodeBlocks, NT, 0, stream>>>(x, deg, dinv, u, N);
        fb_edge1<<<edgeBlocks, NT, 0, stream>>>(src, dst, u, agg1, E);
        fb_node2<<<nodeBlocks, NT, 0, stream>>>(agg1, u, dinv, W1, b1, W2, q, N);
        fb_edge2<<<edgeBlocks, NT, 0, stream>>>(src, dst, q, agg2, E);
        fb_node3<<<nodeBlocks, NT, 0, stream>>>(agg2, q, dinv, b2, (float2*)d_out, N);
    }
}